// Round 1
// 953.178 us; speedup vs baseline: 1.0254x; 1.0254x over previous
//
#include <hip/hip_runtime.h>
#include <cstdint>
#include <cstdio>

typedef unsigned short u16;
typedef __attribute__((ext_vector_type(8))) short short8;   // 8 bf16 (4 VGPRs)
typedef __attribute__((ext_vector_type(4))) float f32x4;

#define DEVFN __device__ __forceinline__

DEVFN u16 f2bf(float f){ union{float f; unsigned u;} v; v.f=f; unsigned r = v.u + 0x7fffu + ((v.u>>16)&1u); return (u16)(r>>16); }
DEVFN float bf2f(u16 h){ union{unsigned u; float f;} v; v.u = ((unsigned)h)<<16; return v.f; }

// async global->LDS, 16B per lane (dwordx4). LDS dest must be wave-uniform base + lane*16.
#define GLOAD_LDS16(gp, lp) __builtin_amdgcn_global_load_lds( \
    (const __attribute__((address_space(1))) void*)(gp), \
    (__attribute__((address_space(3))) void*)(lp), 16, 0, 0)

// ---------------- problem constants ----------------
static constexpr int NTOK = 65536;   // H*W
static constexpr int GSPLIT = 32;    // split-K slabs for Gram
static constexpr int GKLEN  = NTOK / GSPLIT;

// ---------------- workspace layout (bytes) ----------------
static constexpr size_t MB = 1024 * 1024;
static constexpr size_t OFF_XB    = 0;          // bf16 x  [n][c]    64 MiB
static constexpr size_t OFF_XBT   = 64 * MB;    // bf16 x^T [c][n]   64 MiB   (alias: GT)
static constexpr size_t OFF_VB    = 128 * MB;   // bf16 v_inp [n][c] 64 MiB   (gated in-place by k_maskmm)
static constexpr size_t OFF_VT    = 192 * MB;   // bf16 v^T [c][n]   64 MiB
static constexpr size_t OFF_GPART = 256 * MB;   // fp32 [32][512][512] 32 MiB (alias: P patch matrix 25.2 MiB)
static constexpr size_t OFF_G     = 288 * MB;
static constexpr size_t OFF_TQ    = 289 * MB;
static constexpr size_t OFF_TK    = 290 * MB;
static constexpr size_t OFF_WVT   = 291 * MB;            // bf16 Wv^T
static constexpr size_t OFF_W2T   = 291 * MB + 524288;   // bf16 W2^T
static constexpr size_t OFF_ASAR  = 292 * MB;            // fp32 [2][65536]
static constexpr size_t OFF_SS    = 292 * MB + 524288;   // fp32 [2][65536]
static constexpr size_t OFF_BNP   = 293 * MB;
static constexpr size_t OFF_QN    = 293 * MB + 4096;
static constexpr size_t OFF_KN    = 293 * MB + 8192;
static constexpr size_t OFF_ATTN  = 293 * MB + 12288;    // fp32 [8][64][64] = 128 KiB
static constexpr size_t OFF_BM    = 293 * MB + 262144;   // bf16 [1024][192] mask-GEMM weights (384 KiB)
static constexpr size_t OFF_TB    = 293 * MB + 786432;   // fp32 [512][32] border tables (64 KiB)
static constexpr size_t WS_NEEDED = 294 * MB;

// =====================================================================
// bf16 MFMA GEMM: C[M][512] = A[M][K] * B with B stored as [N][K] (B^T).
// 128x128 tile, 4 waves 2x2, wave = 64x64 via 4x4 16x16x32 frags.
// Staging via global_load_lds width=16 (m97 pattern).
// MODE 0: bf16 C. MODE 1: fp32 partial slab (split-K, z). MODE 2: fp32 C + bias.
// =====================================================================
template<int MODE>
__global__ __launch_bounds__(256) void gemm_bt(
    const u16* __restrict__ A, int lda,
    const u16* __restrict__ B, int ldb,
    int klen,
    void* __restrict__ Cout,
    const float* __restrict__ bias)
{
  __shared__ uint4 smem[1024];  // A tile [0..511] = 128x32 bf16 (64B rows); B tile [512..1023]
  const int tid  = threadIdx.x;
  const int lane = tid & 63;
  const int wv   = tid >> 6;
  const int wm   = (wv >> 1) * 64;
  const int wn   = (wv & 1) * 64;
  const int m0   = blockIdx.x * 128;
  const int n0   = blockIdx.y * 128;
  const int kb   = blockIdx.z * klen;

  const int q0 = tid, q1 = tid + 256;
  const size_t arow0 = (size_t)(m0 + (q0 >> 2)) * lda + (q0 & 3) * 8;
  const size_t arow1 = (size_t)(m0 + (q1 >> 2)) * lda + (q1 & 3) * 8;
  const size_t brow0 = (size_t)(n0 + (q0 >> 2)) * ldb + (q0 & 3) * 8;
  const size_t brow1 = (size_t)(n0 + (q1 >> 2)) * ldb + (q1 & 3) * 8;

  f32x4 acc[4][4] = {};
  const char* lAc = (const char*)smem;
  const char* lBc = (const char*)(smem + 512);
  const int ko = (lane >> 4) * 16;
  const int ma = lane & 15;

  for (int k0 = kb; k0 < kb + klen; k0 += 32) {
    __syncthreads();                      // all waves done reading previous tile
    GLOAD_LDS16(&A[arow0 + k0], &smem[q0]);
    GLOAD_LDS16(&A[arow1 + k0], &smem[q1]);
    GLOAD_LDS16(&B[brow0 + k0], &smem[512 + q0]);
    GLOAD_LDS16(&B[brow1 + k0], &smem[512 + q1]);
    __syncthreads();                      // drains vmcnt -> LDS data visible
    short8 af[4], bfr[4];
#pragma unroll
    for (int mt = 0; mt < 4; mt++)
      af[mt] = *(const short8*)(lAc + (wm + mt * 16 + ma) * 64 + ko);
#pragma unroll
    for (int nt = 0; nt < 4; nt++)
      bfr[nt] = *(const short8*)(lBc + (wn + nt * 16 + ma) * 64 + ko);
#pragma unroll
    for (int mt = 0; mt < 4; mt++)
#pragma unroll
      for (int nt = 0; nt < 4; nt++)
        acc[mt][nt] = __builtin_amdgcn_mfma_f32_16x16x32_bf16(af[mt], bfr[nt], acc[mt][nt], 0, 0, 0);
  }

  const int col = lane & 15;
  const int rq  = (lane >> 4) * 4;
  float* Cf = (float*)Cout;
  u16*   Ch = (u16*)Cout;
  if (MODE == 1) Cf += (size_t)blockIdx.z * 512 * 512;
#pragma unroll
  for (int mt = 0; mt < 4; mt++) {
#pragma unroll
    for (int nt = 0; nt < 4; nt++) {
      const int mbase = m0 + wm + mt * 16 + rq;
      const int nn    = n0 + wn + nt * 16 + col;
#pragma unroll
      for (int r = 0; r < 4; r++) {
        float vv = acc[mt][nt][r];
        size_t idx = (size_t)(mbase + r) * 512 + nn;
        if (MODE == 0)      Ch[idx] = f2bf(vv);
        else if (MODE == 1) Cf[idx] = vv;
        else                Cf[idx] = vv + bias[nn];
      }
    }
  }
}

// ---------------- x fp32 [n][512] -> bf16 xb [n][512] and xbT [512][n] ----------------
__global__ void k_cast_transpose(const float* __restrict__ x, u16* __restrict__ xb, u16* __restrict__ xbT)
{
  __shared__ u16 tile[64][72];
  const int t0 = blockIdx.x * 64, c0 = blockIdx.y * 64;
  const int tx = threadIdx.x & 15, ty = threadIdx.x >> 4;
#pragma unroll
  for (int p = 0; p < 4; p++) {
    int t = ty + p * 16;
    float4 v = *(const float4*)&x[(size_t)(t0 + t) * 512 + c0 + tx * 4];
    ushort4 u; u.x = f2bf(v.x); u.y = f2bf(v.y); u.z = f2bf(v.z); u.w = f2bf(v.w);
    *(ushort4*)&xb[(size_t)(t0 + t) * 512 + c0 + tx * 4] = u;
    tile[t][tx*4+0] = u.x; tile[t][tx*4+1] = u.y; tile[t][tx*4+2] = u.z; tile[t][tx*4+3] = u.w;
  }
  __syncthreads();
#pragma unroll
  for (int p = 0; p < 4; p++) {
    int c = ty + p * 16;
    ushort4 u;
    u.x = tile[tx*4+0][c]; u.y = tile[tx*4+1][c]; u.z = tile[tx*4+2][c]; u.w = tile[tx*4+3][c];
    *(ushort4*)&xbT[(size_t)(c0 + c) * 65536 + t0 + tx * 4] = u;
  }
}

// ---------------- generic bf16 tiled transpose: src[srows][scols] -> dst[scols][srows] ----------------
__global__ void k_tbf16(const u16* __restrict__ src, u16* __restrict__ dst, int srows, int scols)
{
  __shared__ u16 tile[64][72];
  const int r0 = blockIdx.x * 64, c0v = blockIdx.y * 64;
  const int tx = threadIdx.x & 15, ty = threadIdx.x >> 4;
#pragma unroll
  for (int p = 0; p < 4; p++) {
    int r = ty + p * 16;
    ushort4 u = *(const ushort4*)&src[(size_t)(r0 + r) * scols + c0v + tx * 4];
    tile[r][tx*4+0] = u.x; tile[r][tx*4+1] = u.y; tile[r][tx*4+2] = u.z; tile[r][tx*4+3] = u.w;
  }
  __syncthreads();
#pragma unroll
  for (int p = 0; p < 4; p++) {
    int c = ty + p * 16;
    ushort4 u;
    u.x = tile[tx*4+0][c]; u.y = tile[tx*4+1][c]; u.z = tile[tx*4+2][c]; u.w = tile[tx*4+3][c];
    *(ushort4*)&dst[(size_t)(c0v + c) * srows + r0 + tx * 4] = u;
  }
}

// ---------------- W fp32 [512][512] -> bf16 W^T ----------------
__global__ void k_transpose_w(const float* __restrict__ Wsrc, u16* __restrict__ WT)
{
  __shared__ u16 tile[64][72];
  const int k0 = blockIdx.x * 64, n0 = blockIdx.y * 64;
  const int tx = threadIdx.x & 15, ty = threadIdx.x >> 4;
#pragma unroll
  for (int p = 0; p < 4; p++) {
    int t = ty + p * 16;
    float4 v = *(const float4*)&Wsrc[(size_t)(k0 + t) * 512 + n0 + tx * 4];
    tile[t][tx*4+0] = f2bf(v.x); tile[t][tx*4+1] = f2bf(v.y);
    tile[t][tx*4+2] = f2bf(v.z); tile[t][tx*4+3] = f2bf(v.w);
  }
  __syncthreads();
#pragma unroll
  for (int p = 0; p < 4; p++) {
    int c = ty + p * 16;
    ushort4 u;
    u.x = tile[tx*4+0][c]; u.y = tile[tx*4+1][c]; u.z = tile[tx*4+2][c]; u.w = tile[tx*4+3][c];
    *(ushort4*)&WT[(size_t)(n0 + c) * 512 + k0 + tx * 4] = u;
  }
}

// ---------------- reduce Gram partials ----------------
__global__ void k_reduce_g(const float* __restrict__ part, float* __restrict__ G)
{
  const int i = blockIdx.x * 256 + threadIdx.x;
  float s = 0.f;
  for (int z = 0; z < GSPLIT; z++) s += part[(size_t)z * 262144 + i];
  G[i] = s;
}

// ---------------- Tq = G@Wq, Tk = G@Wk ----------------
__global__ __launch_bounds__(256) void k_gw(const float* __restrict__ G,
    const float* __restrict__ Wq, const float* __restrict__ Wk,
    float* __restrict__ Tq, float* __restrict__ Tk)
{
  const float* Bm = blockIdx.z ? Wk : Wq;
  float* Cm = blockIdx.z ? Tk : Tq;
  __shared__ float As[64][68];
  __shared__ float Bs[64][68];
  const int i0 = blockIdx.x * 64, j0 = blockIdx.y * 64;
  const int tx = threadIdx.x & 15, ty = threadIdx.x >> 4;
  float acc[4][4] = {};
  for (int k0 = 0; k0 < 512; k0 += 64) {
    __syncthreads();
#pragma unroll
    for (int p = 0; p < 4; p++) {
      int r = ty + p * 16;
      float4 a = *(const float4*)&G [(size_t)(i0 + r) * 512 + k0 + tx * 4];
      float4 b = *(const float4*)&Bm[(size_t)(k0 + r) * 512 + j0 + tx * 4];
      *(float4*)&As[r][tx * 4] = a;
      *(float4*)&Bs[r][tx * 4] = b;
    }
    __syncthreads();
    for (int kk = 0; kk < 64; kk++) {
      float a0 = As[ty*4+0][kk], a1 = As[ty*4+1][kk], a2 = As[ty*4+2][kk], a3 = As[ty*4+3][kk];
      float4 bq = *(const float4*)&Bs[kk][tx * 4];
      acc[0][0] += a0*bq.x; acc[0][1] += a0*bq.y; acc[0][2] += a0*bq.z; acc[0][3] += a0*bq.w;
      acc[1][0] += a1*bq.x; acc[1][1] += a1*bq.y; acc[1][2] += a1*bq.z; acc[1][3] += a1*bq.w;
      acc[2][0] += a2*bq.x; acc[2][1] += a2*bq.y; acc[2][2] += a2*bq.z; acc[2][3] += a2*bq.w;
      acc[3][0] += a3*bq.x; acc[3][1] += a3*bq.y; acc[3][2] += a3*bq.z; acc[3][3] += a3*bq.w;
    }
  }
#pragma unroll
  for (int u = 0; u < 4; u++) {
    float4 o = make_float4(acc[u][0], acc[u][1], acc[u][2], acc[u][3]);
    *(float4*)&Cm[(size_t)(i0 + ty * 4 + u) * 512 + j0 + tx * 4] = o;
  }
}

// ---------------- norms ----------------
__global__ void k_norms(const float* __restrict__ Wq, const float* __restrict__ Tq,
                        const float* __restrict__ Wk, const float* __restrict__ Tk,
                        float* __restrict__ qn, float* __restrict__ kn)
{
  const int gw = (blockIdx.x * 256 + threadIdx.x) >> 6;
  const int lane = threadIdx.x & 63;
  const float* Wm = (gw < 512) ? Wq : Wk;
  const float* Tm = (gw < 512) ? Tq : Tk;
  const int c = gw & 511;
  float s = 0.f;
  for (int r = lane; r < 512; r += 64) s += Wm[(size_t)r * 512 + c] * Tm[(size_t)r * 512 + c];
  for (int off = 32; off > 0; off >>= 1) s += __shfl_down(s, off);
  if (lane == 0) {
    float n = sqrtf(fmaxf(s, 0.f));
    ((gw < 512) ? qn : kn)[c] = fmaxf(n, 1e-12f);
  }
}

// ---------------- per-head logits + softmax ----------------
__global__ __launch_bounds__(256) void k_attn(const float* __restrict__ Wk, const float* __restrict__ Tq,
    const float* __restrict__ qn, const float* __restrict__ kn,
    const float* __restrict__ rescale, float* __restrict__ attn)
{
  const int h = blockIdx.x, hd = h * 64;
  __shared__ float Ks[64][68];
  __shared__ float Qs[64][68];
  __shared__ float Ss[64][65];
  const int tx = threadIdx.x & 15, ty = threadIdx.x >> 4;
  float acc[4][4] = {};
  for (int k0 = 0; k0 < 512; k0 += 64) {
    __syncthreads();
#pragma unroll
    for (int p = 0; p < 4; p++) {
      int r = ty + p * 16;
      float4 a = *(const float4*)&Wk[(size_t)(k0 + r) * 512 + hd + tx * 4];
      float4 b = *(const float4*)&Tq[(size_t)(k0 + r) * 512 + hd + tx * 4];
      *(float4*)&Ks[r][tx * 4] = a;
      *(float4*)&Qs[r][tx * 4] = b;
    }
    __syncthreads();
    for (int kk = 0; kk < 64; kk++) {
      float a0 = Ks[kk][ty*4+0], a1 = Ks[kk][ty*4+1], a2 = Ks[kk][ty*4+2], a3 = Ks[kk][ty*4+3];
      float4 bq = *(const float4*)&Qs[kk][tx * 4];
      acc[0][0] += a0*bq.x; acc[0][1] += a0*bq.y; acc[0][2] += a0*bq.z; acc[0][3] += a0*bq.w;
      acc[1][0] += a1*bq.x; acc[1][1] += a1*bq.y; acc[1][2] += a1*bq.z; acc[1][3] += a1*bq.w;
      acc[2][0] += a2*bq.x; acc[2][1] += a2*bq.y; acc[2][2] += a2*bq.z; acc[2][3] += a2*bq.w;
      acc[3][0] += a3*bq.x; acc[3][1] += a3*bq.y; acc[3][2] += a3*bq.z; acc[3][3] += a3*bq.w;
    }
  }
#pragma unroll
  for (int u = 0; u < 4; u++)
#pragma unroll
    for (int v = 0; v < 4; v++)
      Ss[ty * 4 + u][tx * 4 + v] = acc[u][v];
  __syncthreads();
  if (threadIdx.x < 64) {
    const int i = threadIdx.x;
    const float sci = rescale[h] / kn[hd + i];
    float mx = -1e30f;
    for (int j = 0; j < 64; j++) {
      float L = Ss[i][j] * sci / qn[hd + j];
      Ss[i][j] = L;
      mx = fmaxf(mx, L);
    }
    float sum = 0.f;
    for (int j = 0; j < 64; j++) { float e = __expf(Ss[i][j] - mx); Ss[i][j] = e; sum += e; }
    float inv = 1.f / sum;
    for (int j = 0; j < 64; j++) attn[(size_t)h * 4096 + i * 64 + j] = Ss[i][j] * inv;
  }
}

// ---------------- fold attn into Wp ----------------
__global__ void k_w2t(const float* __restrict__ attn, const float* __restrict__ Wp, u16* __restrict__ W2T)
{
  const int h = blockIdx.x >> 3, e0 = (blockIdx.x & 7) * 64;
  __shared__ float As[64][65];
  for (int p = 0; p < 16; p++) {
    int idx = p * 256 + threadIdx.x;
    As[idx >> 6][idx & 63] = attn[(size_t)h * 4096 + idx];
  }
  __syncthreads();
  const int e = e0 + (threadIdx.x & 63);
  const int j4 = threadIdx.x >> 6;
  float s[16];
#pragma unroll
  for (int jj = 0; jj < 16; jj++) s[jj] = 0.f;
  for (int i = 0; i < 64; i++) {
    float wv_ = Wp[(size_t)(h * 64 + i) * 512 + e];
#pragma unroll
    for (int jj = 0; jj < 16; jj++) s[jj] += As[i][j4 * 16 + jj] * wv_;
  }
#pragma unroll
  for (int jj = 0; jj < 16; jj++)
    W2T[(size_t)e * 512 + h * 64 + j4 * 16 + jj] = f2bf(s[jj]);
}

// ---------------- SAR branch ----------------
__global__ void k_conv3(const float* __restrict__ sar, const float* __restrict__ w3,
                        const float* __restrict__ b3, float* __restrict__ a)
{
  const int oc = blockIdx.y;
  const int p = blockIdx.x * 256 + threadIdx.x;
  const int y = p >> 8, x = p & 255;
  float s = b3[oc];
#pragma unroll
  for (int ic = 0; ic < 2; ic++) {
    const float* img = sar + ic * 65536;
    const float* w = w3 + oc * 18 + ic * 9;
#pragma unroll
    for (int k = 0; k < 9; k++) {
      int yy = y + k / 3 - 1, xx = x + k % 3 - 1;
      if ((unsigned)yy < 256u && (unsigned)xx < 256u) s += w[k] * img[yy * 256 + xx];
    }
  }
  a[oc * 65536 + p] = s;
}

__global__ void k_bnstats(const float* __restrict__ a, const float* __restrict__ g,
                          const float* __restrict__ b, float* __restrict__ bnp)
{
  const int ch = blockIdx.x;
  const int tid = threadIdx.x;
  const float* src = a + ch * 65536;
  float s = 0.f, sq = 0.f;
  for (int i = tid; i < 65536; i += 256) { float v = src[i]; s += v; sq += v * v; }
  __shared__ float rs[256], rq[256];
  rs[tid] = s; rq[tid] = sq;
  __syncthreads();
  for (int o = 128; o > 0; o >>= 1) {
    if (tid < o) { rs[tid] += rs[tid + o]; rq[tid] += rq[tid + o]; }
    __syncthreads();
  }
  if (tid == 0) {
    float mu = rs[0] * (1.f / 65536.f);
    float var = rq[0] * (1.f / 65536.f) - mu * mu;
    float scale = g[ch] / sqrtf(var + 1e-5f);
    bnp[ch] = scale;
    bnp[2 + ch] = b[ch] - mu * scale;
  }
}

__global__ void k_sar2(const float* __restrict__ a, const float* __restrict__ bnp,
                       const float* __restrict__ sb, float* __restrict__ ss)
{
  const int p = blockIdx.x * 256 + threadIdx.x;
  const int y = p >> 8, x = p & 255;
  const float sc0 = bnp[0], sc1 = bnp[1], sh0 = bnp[2], sh1 = bnp[3];
  float bs[9];
  float bn0c = 0.f, bn1c = 0.f;
#pragma unroll
  for (int k = 0; k < 9; k++) {
    int yy = y + k / 3 - 1, xx = x + k % 3 - 1;
    float v0 = 0.f, v1 = 0.f;
    if ((unsigned)yy < 256u && (unsigned)xx < 256u) {
      int q = yy * 256 + xx;
      v0 = a[q] * sc0 + sh0;
      v1 = a[65536 + q] * sc1 + sh1;
    }
    bs[k] = v0 + v1;
    if (k == 4) { bn0c = v0; bn1c = v1; }
  }
  float gv = (bs[6] + 2.f * bs[7] + bs[8]) - (bs[0] + 2.f * bs[1] + bs[2]);
  float gh = (bs[2] + 2.f * bs[5] + bs[8]) - (bs[0] + 2.f * bs[3] + bs[6]);
  float s0 = gv + sb[0], s1 = gh + sb[1], s2 = gv + sb[2], s3 = gh + sb[3];
  ss[p]         = sqrtf(s0 * s0 + s1 * s1) + bn0c;
  ss[65536 + p] = sqrtf(s2 * s2 + s3 * s3) + bn1c;
}

// =====================================================================
// Mask via MFMA GEMM. The mask for pixel p, channel c is
//   mask = L1(p,c) + beta_c*(W(p)-wsum_c) + sigmoid(L2(p,c))
// where L1, L2 are linear in the 50-value patch (5x5 window of the 2 SAR
// planes, zero-padded). Both are computed with one bf16 GEMM, hi/lo
// compensated: K=192 = 3 blocks of 64:
//   k[0..63]    A = hi(taps), +1.0 at slot 63      B = hi(coeffs), bias at 63
//   k[64..127]  A = lo(taps), 0 at slot 127        B = hi(coeffs)  (copy)
//   k[128..191] A = hi(taps), +1.0 at slot 191     B = lo(coeffs), bias-lo at 63
// => L = sum hi*hi + lo*hi + hi*lo  (error ~2^-17 relative).
// L1 coeffs fold in e1's center term and constant C1 = beta*(1+wsum)+db.
// Border indicator conv handled exactly via inclusion-exclusion tables.
// =====================================================================

// ---- k_dwprep: build BM [1024][192] bf16 and border tables TB [512][32] ----
__global__ void k_dwprep(const float* __restrict__ dw, const float* __restrict__ db,
                         const float* __restrict__ w2, const float* __restrict__ b2,
                         const float* __restrict__ w32, const float* __restrict__ b32,
                         u16* __restrict__ BM, float* __restrict__ TB)
{
  const int c = blockIdx.x * 256 + threadIdx.x;
  if (c >= 512) return;
  float d[25];
  float wsum = 0.f;
#pragma unroll
  for (int t = 0; t < 25; t++) { d[t] = dw[c * 25 + t]; wsum += d[t]; }
  const float a = w2[2 * c], b = w2[2 * c + 1], beta = b2[c];
  const float C1 = beta * (1.f + wsum) + db[c];

  u16* rL1 = BM + (size_t)((c >> 6) * 128 + (c & 63)) * 192;
  u16* rL2 = rL1 + (size_t)64 * 192;

#pragma unroll
  for (int k = 0; k < 64; k++) {
    float v1;
    if (k < 25)       v1 = a * (d[k] + (k == 12 ? 1.f : 0.f));
    else if (k < 50)  v1 = b * (d[k - 25] + (k == 37 ? 1.f : 0.f));
    else if (k == 63) v1 = C1;
    else              v1 = 0.f;
    u16 h = f2bf(v1); u16 l = f2bf(v1 - bf2f(h));
    rL1[k] = h; rL1[64 + k] = h; rL1[128 + k] = l;
  }
#pragma unroll
  for (int k = 0; k < 64; k++) {
    float v2 = 0.f;
    if (k < 50) {
      const int t = (k < 25) ? k : (k - 25);
      const int dy = t / 5 - 2, dx = t % 5 - 2;
      if (dy >= -1 && dy <= 1 && dx >= -1 && dx <= 1)
        v2 = w32[c * 18 + ((k < 25) ? 0 : 9) + (dy + 1) * 3 + (dx + 1)];
    }
    if (k == 63) v2 = b32[c];
    u16 h = f2bf(v2); u16 l = f2bf(v2 - bf2f(h));
    rL2[k] = h; rL2[64 + k] = h; rL2[128 + k] = l;
  }

  // border tables: W = wsum - T[mt] - B[mb] - L[ml] - R[mr] + corners
  float rs[5], cs[5];
#pragma unroll
  for (int i = 0; i < 5; i++) {
    rs[i] = d[i*5] + d[i*5+1] + d[i*5+2] + d[i*5+3] + d[i*5+4];
    cs[i] = d[i] + d[5+i] + d[10+i] + d[15+i] + d[20+i];
  }
  float* tb = TB + (size_t)c * 32;
  tb[0] = rs[0];  tb[1] = rs[0] + rs[1];          // T1, T2 (missing top rows)
  tb[2] = rs[4];  tb[3] = rs[3] + rs[4];          // B1, B2
  tb[4] = cs[0];  tb[5] = cs[0] + cs[1];          // L1, L2
  tb[6] = cs[4];  tb[7] = cs[3] + cs[4];          // R1, R2
  tb[8]  = d[0];           tb[9]  = d[0] + d[1];            // TL(1,1) TL(1,2)
  tb[10] = d[0] + d[5];    tb[11] = d[0] + d[1] + d[5] + d[6];
  tb[12] = d[4];           tb[13] = d[3] + d[4];            // TR
  tb[14] = d[4] + d[9];    tb[15] = d[3] + d[4] + d[8] + d[9];
  tb[16] = d[20];          tb[17] = d[20] + d[21];          // BL
  tb[18] = d[15] + d[20];  tb[19] = d[15] + d[16] + d[20] + d[21];
  tb[20] = d[24];          tb[21] = d[23] + d[24];          // BR
  tb[22] = d[19] + d[24];  tb[23] = d[18] + d[19] + d[23] + d[24];
#pragma unroll
  for (int i = 24; i < 32; i++) tb[i] = 0.f;
}

// ---- k_patch: build P [65536][192] bf16 patch matrix from SS ----
__global__ __launch_bounds__(256) void k_patch(const float* __restrict__ ss, u16* __restrict__ P)
{
  __shared__ float s0r[5][264];
  __shared__ float s1r[5][264];
  const int y = blockIdx.x;       // one image row per block
  const int tid = threadIdx.x;
  for (int i = tid; i < 1300; i += 256) {
    const int r = i / 260, col = i - r * 260;
    const int yy = y + r - 2, xx = col - 2;
    const bool in = ((unsigned)yy < 256u) & ((unsigned)xx < 256u);
    const int gp = yy * 256 + xx;
    s0r[r][col] = in ? ss[gp] : 0.f;
    s1r[r][col] = in ? ss[65536 + gp] : 0.f;
  }
  __syncthreads();
  const int x = tid;
  unsigned arr32[64];              // k[0..127]; k[128..191] is a copy of k[0..63]
#pragma unroll
  for (int i = 0; i < 64; i++) arr32[i] = 0u;
#define PUTK(k, v) arr32[(k) >> 1] |= ((unsigned)(v)) << (((k) & 1) * 16)
#pragma unroll
  for (int dy = 0; dy < 5; dy++)
#pragma unroll
    for (int dx = 0; dx < 5; dx++) {
      const int t = dy * 5 + dx;
      const float v0 = s0r[dy][x + dx];
      const float v1 = s1r[dy][x + dx];
      const u16 h0 = f2bf(v0); const u16 l0 = f2bf(v0 - bf2f(h0));
      const u16 h1 = f2bf(v1); const u16 l1 = f2bf(v1 - bf2f(h1));
      PUTK(t, h0);      PUTK(25 + t, h1);
      PUTK(64 + t, l0); PUTK(89 + t, l1);
    }
  PUTK(63, 0x3F80u);               // 1.0 for bias slot (block2 copy gives k191=1.0)
#undef PUTK
  unsigned* dst = (unsigned*)(P + (size_t)(y * 256 + x) * 192);
#pragma unroll
  for (int i = 0; i < 16; i++)
    *(uint4*)(dst + i * 4) = *(const uint4*)(arr32 + i * 4);
#pragma unroll
  for (int i = 0; i < 8; i++)
    *(uint4*)(dst + 64 + i * 4) = *(const uint4*)(arr32 + i * 4);
}

// ---- k_maskmm: C = P @ BM^T fused with sigmoid/border/V-gate, in-place VB ----
// Tile: M=128 px, N=128 (64 ch: n<64 -> L1, n>=64 -> L2), K=192 (no outer loop).
// 4 waves stacked in M (wave tile 32x128) so each lane holds L1 and L2 of the
// SAME channel (frag nt and nt+4, same lane) -> epilogue is lane-local.
__global__ __launch_bounds__(256) void k_maskmm(
    const u16* __restrict__ P, const u16* __restrict__ BM,
    const float* __restrict__ TB, const float* __restrict__ beta_p,
    u16* __restrict__ VB)
{
  __shared__ uint4 smem[1024];  // A tile 128x32 (64B rows) ; B tile 128x32
  const int tid  = threadIdx.x;
  const int lane = tid & 63;
  const int wv   = tid >> 6;
  const int m0   = blockIdx.x * 128;
  const int g    = blockIdx.y;          // channel group (64 ch)

  const int q0 = tid, q1 = tid + 256;
  const size_t arow0 = (size_t)(m0 + (q0 >> 2)) * 192 + (q0 & 3) * 8;
  const size_t arow1 = (size_t)(m0 + (q1 >> 2)) * 192 + (q1 & 3) * 8;
  const size_t brow0 = (size_t)(g * 128 + (q0 >> 2)) * 192 + (q0 & 3) * 8;
  const size_t brow1 = (size_t)(g * 128 + (q1 >> 2)) * 192 + (q1 & 3) * 8;

  f32x4 acc[2][8] = {};
  const char* lAc = (const char*)smem;
  const char* lBc = (const char*)(smem + 512);
  const int ko = (lane >> 4) * 16;
  const int ma = lane & 15;

  for (int k0 = 0; k0 < 192; k0 += 32) {
    __syncthreads();
    GLOAD_LDS16(&P[arow0 + k0],  &smem[q0]);
    GLOAD_LDS16(&P[arow1 + k0],  &smem[q1]);
    GLOAD_LDS16(&BM[brow0 + k0], &smem[512 + q0]);
    GLOAD_LDS16(&BM[brow1 + k0], &smem[512 + q1]);
    __syncthreads();
    short8 af[2], bfr[8];
#pragma unroll
    for (int mt = 0; mt < 2; mt++)
      af[mt] = *(const short8*)(lAc + (wv * 32 + mt * 16 + ma) * 64 + ko);
#pragma unroll
    for (int nt = 0; nt < 8; nt++)
      bfr[nt] = *(const short8*)(lBc + (nt * 16 + ma) * 64 + ko);
#pragma unroll
    for (int mt = 0; mt < 2; mt++)
#pragma unroll
      for (int nt = 0; nt < 8; nt++)
        acc[mt][nt] = __builtin_amdgcn_mfma_f32_16x16x32_bf16(af[mt], bfr[nt], acc[mt][nt], 0, 0, 0);
  }

  const int col = lane & 15, rq = (lane >> 4) * 4;
  const int y   = m0 >> 8;                       // block covers half a row: y uniform
  const int mty = (y < 2) ? (2 - y) : 0;
  const int mby = (y > 253) ? (y - 253) : 0;
#pragma unroll
  for (int mt = 0; mt < 2; mt++) {
#pragma unroll
    for (int nt = 0; nt < 4; nt++) {
      const int ch = g * 64 + nt * 16 + col;
#pragma unroll
      for (int r = 0; r < 4; r++) {
        const int px = m0 + wv * 32 + mt * 16 + rq + r;
        const float L1 = acc[mt][nt][r];
        const float L2 = acc[mt][nt + 4][r];
        const int x  = px & 255;
        const int ml = (x < 2) ? (2 - x) : 0;
        const int mr = (x > 253) ? (x - 253) : 0;
        float wc = 0.f;
        if (mty | mby | ml | mr) {
          const float* tb = &TB[(size_t)ch * 32];
          float W = 0.f;
          if (mty) W -= tb[mty - 1];
          if (mby) W -= tb[2 + mby - 1];
          if (ml)  W -= tb[4 + ml - 1];
          if (mr)  W -= tb[6 + mr - 1];
          if (mty && ml) W += tb[8  + (mty - 1) * 2 + (ml - 1)];
          if (mty && mr) W += tb[12 + (mty - 1) * 2 + (mr - 1)];
          if (mby && ml) W += tb[16 + (mby - 1) * 2 + (ml - 1)];
          if (mby && mr) W += tb[20 + (mby - 1) * 2 + (mr - 1)];
          wc = beta_p[ch] * W;
        }
        const float sig  = 1.f / (1.f + __expf(-L2));
        const float mask = L1 + wc + sig;
        const size_t idx = (size_t)px * 512 + ch;
        VB[idx] = f2bf(bf2f(VB[idx]) * mask);
      }
    }
  }
}

// =====================================================================
// Vectorized depthwise 3x3 (plane layout). Wave = 16 x-subgroups x 4 channels;
// lane loads ushort4 per row, halo via shfl; edge subgroups do predicated u16 load.
// =====================================================================
DEVFN void dw3x3_row4(const u16* plane, int y, int x0, int sub,
                      const float* w9, float& s0, float& s1, float& s2, float& s3)
{
#pragma unroll
  for (int r = 0; r < 3; r++) {
    int yy = y + r - 1;
    if ((unsigned)yy < 256u) {       // block-uniform branch
      const int base = yy * 256 + x0 + sub * 4;
      ushort4 p = *(const ushort4*)&plane[base];
      float v0 = bf2f(p.x), v1 = bf2f(p.y), v2 = bf2f(p.z), v3 = bf2f(p.w);
      float lf = __shfl_up(v3, 1);
      float rt = __shfl_down(v0, 1);
      if (sub == 0)  lf = (x0 > 0)   ? bf2f(plane[yy * 256 + x0 - 1])  : 0.f;
      if (sub == 15) rt = (x0 < 192) ? bf2f(plane[yy * 256 + x0 + 64]) : 0.f;
      const float wa = w9[r * 3], wb = w9[r * 3 + 1], wc = w9[r * 3 + 2];
      s0 += wa * lf + wb * v0 + wc * v1;
      s1 += wa * v0 + wb * v1 + wc * v2;
      s2 += wa * v1 + wb * v2 + wc * v3;
      s3 += wa * v2 + wb * v3 + wc * rt;
    }
  }
}

// pe1: dconv3x3(VT) -> exact GELU -> GT (plane layout, vectorized)
__global__ __launch_bounds__(256) void k_pe1v(const u16* __restrict__ vt,
    const float* __restrict__ w, u16* __restrict__ gt)
{
  const int t = blockIdx.x;
  const int y = t >> 2, x0 = (t & 3) * 64;
  const int cg = blockIdx.y * 64;
  const int lane = threadIdx.x & 63, wvq = threadIdx.x >> 6;
  const int sub = lane & 15, chq = lane >> 4;
#pragma unroll
  for (int i = 0; i < 4; i++) {
    const int c = cg + wvq * 16 + i * 4 + chq;
    const u16* plane = vt + (size_t)c * 65536;
    float w9[9];
#pragma unroll
    for (int k = 0; k < 9; k++) w9[k] = w[c * 9 + k];
    float s0 = 0.f, s1 = 0.f, s2 = 0.f, s3 = 0.f;
    dw3x3_row4(plane, y, x0, sub, w9, s0, s1, s2, s3);
    const float ksc = 0.70710678118654752f;
    s0 = 0.5f * s0 * (1.f + erff(s0 * ksc));
    s1 = 0.5f * s1 * (1.f + erff(s1 * ksc));
    s2 = 0.5f * s2 * (1.f + erff(s2 * ksc));
    s3 = 0.5f * s3 * (1.f + erff(s3 * ksc));
    ushort4 o; o.x = f2bf(s0); o.y = f2bf(s1); o.z = f2bf(s2); o.w = f2bf(s3);
    *(ushort4*)&gt[(size_t)c * 65536 + y * 256 + x0 + sub * 4] = o;
  }
}

// pe2: dconv3x3(GT), LDS transpose (conflict-free), float4 RMW add into out[n][c]
__global__ __launch_bounds__(256) void k_pe2v(const u16* __restrict__ gt,
    const float* __restrict__ w, float* __restrict__ out)
{
  __shared__ float tile[64][65];
  const int t = blockIdx.x;
  const int y = t >> 2, x0 = (t & 3) * 64;
  const int cg = blockIdx.y * 64;
  const int lane = threadIdx.x & 63, wvq = threadIdx.x >> 6;
  const int sub = lane & 15, chq = lane >> 4;
#pragma unroll
  for (int i = 0; i < 4; i++) {
    const int cl = wvq * 16 + i * 4 + chq;
    const int c = cg + cl;
    const u16* plane = gt + (size_t)c * 65536;
    float w9[9];
#pragma unroll
    for (int k = 0; k < 9; k++) w9[k] = w[c * 9 + k];
    float s0 = 0.f, s1 = 0.f, s2 = 0.f, s3 = 0.f;
    dw3x3_row4(plane, y, x0, sub, w9, s0, s1, s2, s3);
    tile[cl][sub * 4 + 0] = s0;
    tile[cl][sub * 4 + 1] = s1;
    tile[cl][sub * 4 + 2] = s2;
    tile[cl][sub * 4 + 3] = s3;
  }
  __syncthreads();
#pragma unroll
  for (int k = 0; k < 4; k++) {
    const int idx = k * 256 + threadIdx.x;
    const int q = idx & 15, pl = idx >> 4;
    float4 add = make_float4(tile[q * 4 + 0][pl], tile[q * 4 + 1][pl],
                             tile[q * 4 + 2][pl], tile[q * 4 + 3][pl]);
    float* op = &out[(size_t)(y * 256 + x0 + pl) * 512 + cg + q * 4];
    float4 o = *(float4*)op;
    o.x += add.x; o.y += add.y; o.z += add.z; o.w += add.w;
    *(float4*)op = o;
  }
}

// =====================================================================
extern "C" void kernel_launch(void* const* d_in, const int* in_sizes, int n_in,
                              void* d_out, int out_size, void* d_ws, size_t ws_size,
                              hipStream_t stream)
{
  (void)in_sizes; (void)n_in; (void)out_size;
  const float* x    = (const float*)d_in[0];
  const float* sar  = (const float*)d_in[1];
  const float* Wq   = (const float*)d_in[2];
  const float* Wk   = (const float*)d_in[3];
  const float* Wv   = (const float*)d_in[4];
  const float* resc = (const float*)d_in[5];
  const float* Wp   = (const float*)d_in[6];
  const float* bp   = (const float*)d_in[7];
  const float* pe1w = (const float*)d_in[8];
  const float* pe2w = (const float*)d_in[9];
  const float* w3   = (const float*)d_in[10];
  const float* b3   = (const float*)d_in[11];
  const float* bng  = (const float*)d_in[12];
  const float* bnb  = (const float*)d_in[13];
  const float* sb   = (const float*)d_in[14];
  const float* w2c  = (const float*)d_in[15];
  const float* b2c  = (const float*)d_in[16];
  const float* w32  = (const float*)d_in[17];
  const float* b32  = (const float*)d_in[18];
  const float* dw   = (const float*)d_in[19];
  const float* db   = (const float*)d_in[20];
  float* out = (float*)d_out;

  if (ws_size < WS_NEEDED)
    fprintf(stderr, "MS_MSA: workspace too small: have %zu need %zu\n", ws_size, WS_NEEDED);

  char* ws = (char*)d_ws;
  u16* XB    = (u16*)(ws + OFF_XB);
  u16* XBT   = (u16*)(ws + OFF_XBT);
  u16* VB    = (u16*)(ws + OFF_VB);
  u16* VT    = (u16*)(ws + OFF_VT);
  float* GPART = (float*)(ws + OFF_GPART);
  float* G     = (float*)(ws + OFF_G);
  float* TQ    = (float*)(ws + OFF_TQ);
  float* TK    = (float*)(ws + OFF_TK);
  u16* WVT   = (u16*)(ws + OFF_WVT);
  u16* W2T   = (u16*)(ws + OFF_W2T);
  float* ASAR = (float*)(ws + OFF_ASAR);
  float* SS   = (float*)(ws + OFF_SS);
  float* BNP  = (float*)(ws + OFF_BNP);
  float* QN   = (float*)(ws + OFF_QN);
  float* KN   = (float*)(ws + OFF_KN);
  float* ATTN = (float*)(ws + OFF_ATTN);
  u16*  BM   = (u16*)(ws + OFF_BM);
  float* TBt  = (float*)(ws + OFF_TB);
  u16* GT  = XBT;                 // alias: XBT dead after Gram
  u16* P   = (u16*)(ws + OFF_GPART);  // alias: GPART dead after k_reduce_g

  // --- x -> bf16 (row + transposed) ---
  k_cast_transpose<<<dim3(1024, 8), 256, 0, stream>>>(x, XB, XBT);
  // --- G = X^T X ---
  gemm_bt<1><<<dim3(4, 4, GSPLIT), 256, 0, stream>>>(XBT, NTOK, XBT, NTOK, GKLEN, GPART, nullptr);
  k_reduce_g<<<1024, 256, 0, stream>>>(GPART, G);
  // --- v_inp = x @ Wv ---
  k_transpose_w<<<dim3(8, 8), 256, 0, stream>>>(Wv, WVT);
  gemm_bt<0><<<dim3(512, 4), 256, 0, stream>>>(XB, 512, WVT, 512, 512, VB, nullptr);
  k_tbf16<<<dim3(1024, 8), 256, 0, stream>>>(VB, VT, 65536, 512);   // VT = ungated v^T for pe1
  // --- attention stats ---
  k_gw<<<dim3(8, 8, 2), 256, 0, stream>>>(G, Wq, Wk, TQ, TK);
  k_norms<<<256, 256, 0, stream>>>(Wq, TQ, Wk, TK, QN, KN);
  k_attn<<<8, 256, 0, stream>>>(Wk, TQ, QN, KN, resc, ATTN);
  k_w2t<<<64, 256, 0, stream>>>(ATTN, Wp, W2T);
  // --- SAR branch ---
  k_conv3<<<dim3(256, 2), 256, 0, stream>>>(sar, w3, b3, ASAR);
  k_bnstats<<<2, 256, 0, stream>>>(ASAR, bng, bnb, BNP);
  k_sar2<<<256, 256, 0, stream>>>(ASAR, BNP, sb, SS);
  // --- mask via compensated bf16 MFMA GEMM, gate V in-place ([n][c]) ---
  k_dwprep<<<2, 256, 0, stream>>>(dw, db, w2c, b2c, w32, b32, BM, TBt);
  k_patch<<<256, 256, 0, stream>>>(SS, P);
  k_maskmm<<<dim3(512, 8), 256, 0, stream>>>(P, BM, TBt, b2c, VB);
  // --- out = (v*mask) @ W2 + bp ---
  gemm_bt<2><<<dim3(512, 4), 256, 0, stream>>>(VB, 512, W2T, 512, 512, out, bp);
  // --- positional branch (vectorized) ---
  k_pe1v<<<dim3(1024, 8), 256, 0, stream>>>(VT, pe1w, GT);
  k_pe2v<<<dim3(1024, 8), 256, 0, stream>>>(GT, pe2w, out);
}

// Round 2
// 927.637 us; speedup vs baseline: 1.0536x; 1.0275x over previous
//
#include <hip/hip_runtime.h>
#include <cstdint>
#include <cstdio>

typedef unsigned short u16;
typedef __attribute__((ext_vector_type(8))) short short8;   // 8 bf16 (4 VGPRs)
typedef __attribute__((ext_vector_type(4))) float f32x4;

#define DEVFN __device__ __forceinline__

DEVFN u16 f2bf(float f){ union{float f; unsigned u;} v; v.f=f; unsigned r = v.u + 0x7fffu + ((v.u>>16)&1u); return (u16)(r>>16); }
DEVFN float bf2f(u16 h){ union{unsigned u; float f;} v; v.u = ((unsigned)h)<<16; return v.f; }

// async global->LDS, 16B per lane (dwordx4). LDS dest must be wave-uniform base + lane*16.
#define GLOAD_LDS16(gp, lp) __builtin_amdgcn_global_load_lds( \
    (const __attribute__((address_space(1))) void*)(gp), \
    (__attribute__((address_space(3))) void*)(lp), 16, 0, 0)

// ---------------- problem constants ----------------
static constexpr int NTOK = 65536;   // H*W
static constexpr int GSPLIT = 32;    // split-K slabs for Gram
static constexpr int GKLEN  = NTOK / GSPLIT;

// ---------------- workspace layout (bytes) ----------------
static constexpr size_t MB = 1024 * 1024;
static constexpr size_t OFF_XB    = 0;          // bf16 x  [n][c]    64 MiB
static constexpr size_t OFF_XBT   = 64 * MB;    // bf16 x^T [c][n]   64 MiB   (alias: GT)
static constexpr size_t OFF_VB    = 128 * MB;   // bf16 v_inp [n][c] 64 MiB   (gated in-place by k_maskmm)
static constexpr size_t OFF_VT    = 192 * MB;   // bf16 v^T [c][n]   64 MiB
static constexpr size_t OFF_GPART = 256 * MB;   // fp32 [32][512][512] 32 MiB (alias: P patch matrix 25.2 MiB)
static constexpr size_t OFF_G     = 288 * MB;
static constexpr size_t OFF_TQ    = 289 * MB;
static constexpr size_t OFF_TK    = 290 * MB;
static constexpr size_t OFF_WVT   = 291 * MB;            // bf16 Wv^T
static constexpr size_t OFF_W2T   = 291 * MB + 524288;   // bf16 W2^T
static constexpr size_t OFF_ASAR  = 292 * MB;            // fp32 [2][65536]
static constexpr size_t OFF_SS    = 292 * MB + 524288;   // fp32 [2][65536]
static constexpr size_t OFF_BNP   = 293 * MB;
static constexpr size_t OFF_QN    = 293 * MB + 4096;
static constexpr size_t OFF_KN    = 293 * MB + 8192;
static constexpr size_t OFF_ATTN  = 293 * MB + 12288;    // fp32 [8][64][64] = 128 KiB
static constexpr size_t OFF_BM    = 293 * MB + 262144;   // bf16 [1024][192] mask-GEMM weights (384 KiB)
static constexpr size_t OFF_TB    = 293 * MB + 786432;   // fp32 [512][32] border tables (64 KiB)
static constexpr size_t WS_NEEDED = 294 * MB;

// =====================================================================
// bf16 MFMA GEMM: C[M][512] = A[M][K] * B with B stored as [N][K] (B^T).
// 128x128 tile, 4 waves 2x2, wave = 64x64 via 4x4 16x16x32 frags.
// Staging via global_load_lds width=16 (m97 pattern).
// MODE 0: bf16 C. MODE 1: fp32 partial slab (split-K, z). MODE 2: fp32 C + bias.
// =====================================================================
template<int MODE>
__global__ __launch_bounds__(256) void gemm_bt(
    const u16* __restrict__ A, int lda,
    const u16* __restrict__ B, int ldb,
    int klen,
    void* __restrict__ Cout,
    const float* __restrict__ bias)
{
  __shared__ uint4 smem[1024];  // A tile [0..511] = 128x32 bf16 (64B rows); B tile [512..1023]
  const int tid  = threadIdx.x;
  const int lane = tid & 63;
  const int wv   = tid >> 6;
  const int wm   = (wv >> 1) * 64;
  const int wn   = (wv & 1) * 64;
  const int m0   = blockIdx.x * 128;
  const int n0   = blockIdx.y * 128;
  const int kb   = blockIdx.z * klen;

  const int q0 = tid, q1 = tid + 256;
  const size_t arow0 = (size_t)(m0 + (q0 >> 2)) * lda + (q0 & 3) * 8;
  const size_t arow1 = (size_t)(m0 + (q1 >> 2)) * lda + (q1 & 3) * 8;
  const size_t brow0 = (size_t)(n0 + (q0 >> 2)) * ldb + (q0 & 3) * 8;
  const size_t brow1 = (size_t)(n0 + (q1 >> 2)) * ldb + (q1 & 3) * 8;

  f32x4 acc[4][4] = {};
  const char* lAc = (const char*)smem;
  const char* lBc = (const char*)(smem + 512);
  const int ko = (lane >> 4) * 16;
  const int ma = lane & 15;

  for (int k0 = kb; k0 < kb + klen; k0 += 32) {
    __syncthreads();                      // all waves done reading previous tile
    GLOAD_LDS16(&A[arow0 + k0], &smem[q0]);
    GLOAD_LDS16(&A[arow1 + k0], &smem[q1]);
    GLOAD_LDS16(&B[brow0 + k0], &smem[512 + q0]);
    GLOAD_LDS16(&B[brow1 + k0], &smem[512 + q1]);
    __syncthreads();                      // drains vmcnt -> LDS data visible
    short8 af[4], bfr[4];
#pragma unroll
    for (int mt = 0; mt < 4; mt++)
      af[mt] = *(const short8*)(lAc + (wm + mt * 16 + ma) * 64 + ko);
#pragma unroll
    for (int nt = 0; nt < 4; nt++)
      bfr[nt] = *(const short8*)(lBc + (wn + nt * 16 + ma) * 64 + ko);
#pragma unroll
    for (int mt = 0; mt < 4; mt++)
#pragma unroll
      for (int nt = 0; nt < 4; nt++)
        acc[mt][nt] = __builtin_amdgcn_mfma_f32_16x16x32_bf16(af[mt], bfr[nt], acc[mt][nt], 0, 0, 0);
  }

  const int col = lane & 15;
  const int rq  = (lane >> 4) * 4;
  float* Cf = (float*)Cout;
  u16*   Ch = (u16*)Cout;
  if (MODE == 1) Cf += (size_t)blockIdx.z * 512 * 512;
#pragma unroll
  for (int mt = 0; mt < 4; mt++) {
#pragma unroll
    for (int nt = 0; nt < 4; nt++) {
      const int mbase = m0 + wm + mt * 16 + rq;
      const int nn    = n0 + wn + nt * 16 + col;
#pragma unroll
      for (int r = 0; r < 4; r++) {
        float vv = acc[mt][nt][r];
        size_t idx = (size_t)(mbase + r) * 512 + nn;
        if (MODE == 0)      Ch[idx] = f2bf(vv);
        else if (MODE == 1) Cf[idx] = vv;
        else                Cf[idx] = vv + bias[nn];
      }
    }
  }
}

// ---------------- x fp32 [n][512] -> bf16 xb [n][512] and xbT [512][n] ----------------
__global__ void k_cast_transpose(const float* __restrict__ x, u16* __restrict__ xb, u16* __restrict__ xbT)
{
  __shared__ u16 tile[64][72];
  const int t0 = blockIdx.x * 64, c0 = blockIdx.y * 64;
  const int tx = threadIdx.x & 15, ty = threadIdx.x >> 4;
#pragma unroll
  for (int p = 0; p < 4; p++) {
    int t = ty + p * 16;
    float4 v = *(const float4*)&x[(size_t)(t0 + t) * 512 + c0 + tx * 4];
    ushort4 u; u.x = f2bf(v.x); u.y = f2bf(v.y); u.z = f2bf(v.z); u.w = f2bf(v.w);
    *(ushort4*)&xb[(size_t)(t0 + t) * 512 + c0 + tx * 4] = u;
    tile[t][tx*4+0] = u.x; tile[t][tx*4+1] = u.y; tile[t][tx*4+2] = u.z; tile[t][tx*4+3] = u.w;
  }
  __syncthreads();
#pragma unroll
  for (int p = 0; p < 4; p++) {
    int c = ty + p * 16;
    ushort4 u;
    u.x = tile[tx*4+0][c]; u.y = tile[tx*4+1][c]; u.z = tile[tx*4+2][c]; u.w = tile[tx*4+3][c];
    *(ushort4*)&xbT[(size_t)(c0 + c) * 65536 + t0 + tx * 4] = u;
  }
}

// ---------------- generic bf16 tiled transpose: src[srows][scols] -> dst[scols][srows] ----------------
__global__ void k_tbf16(const u16* __restrict__ src, u16* __restrict__ dst, int srows, int scols)
{
  __shared__ u16 tile[64][72];
  const int r0 = blockIdx.x * 64, c0v = blockIdx.y * 64;
  const int tx = threadIdx.x & 15, ty = threadIdx.x >> 4;
#pragma unroll
  for (int p = 0; p < 4; p++) {
    int r = ty + p * 16;
    ushort4 u = *(const ushort4*)&src[(size_t)(r0 + r) * scols + c0v + tx * 4];
    tile[r][tx*4+0] = u.x; tile[r][tx*4+1] = u.y; tile[r][tx*4+2] = u.z; tile[r][tx*4+3] = u.w;
  }
  __syncthreads();
#pragma unroll
  for (int p = 0; p < 4; p++) {
    int c = ty + p * 16;
    ushort4 u;
    u.x = tile[tx*4+0][c]; u.y = tile[tx*4+1][c]; u.z = tile[tx*4+2][c]; u.w = tile[tx*4+3][c];
    *(ushort4*)&dst[(size_t)(c0v + c) * srows + r0 + tx * 4] = u;
  }
}

// ---------------- W fp32 [512][512] -> bf16 W^T ----------------
__global__ void k_transpose_w(const float* __restrict__ Wsrc, u16* __restrict__ WT)
{
  __shared__ u16 tile[64][72];
  const int k0 = blockIdx.x * 64, n0 = blockIdx.y * 64;
  const int tx = threadIdx.x & 15, ty = threadIdx.x >> 4;
#pragma unroll
  for (int p = 0; p < 4; p++) {
    int t = ty + p * 16;
    float4 v = *(const float4*)&Wsrc[(size_t)(k0 + t) * 512 + n0 + tx * 4];
    tile[t][tx*4+0] = f2bf(v.x); tile[t][tx*4+1] = f2bf(v.y);
    tile[t][tx*4+2] = f2bf(v.z); tile[t][tx*4+3] = f2bf(v.w);
  }
  __syncthreads();
#pragma unroll
  for (int p = 0; p < 4; p++) {
    int c = ty + p * 16;
    ushort4 u;
    u.x = tile[tx*4+0][c]; u.y = tile[tx*4+1][c]; u.z = tile[tx*4+2][c]; u.w = tile[tx*4+3][c];
    *(ushort4*)&WT[(size_t)(n0 + c) * 512 + k0 + tx * 4] = u;
  }
}

// ---------------- reduce Gram partials ----------------
__global__ void k_reduce_g(const float* __restrict__ part, float* __restrict__ G)
{
  const int i = blockIdx.x * 256 + threadIdx.x;
  float s = 0.f;
  for (int z = 0; z < GSPLIT; z++) s += part[(size_t)z * 262144 + i];
  G[i] = s;
}

// ---------------- Tq = G@Wq, Tk = G@Wk ----------------
__global__ __launch_bounds__(256) void k_gw(const float* __restrict__ G,
    const float* __restrict__ Wq, const float* __restrict__ Wk,
    float* __restrict__ Tq, float* __restrict__ Tk)
{
  const float* Bm = blockIdx.z ? Wk : Wq;
  float* Cm = blockIdx.z ? Tk : Tq;
  __shared__ float As[64][68];
  __shared__ float Bs[64][68];
  const int i0 = blockIdx.x * 64, j0 = blockIdx.y * 64;
  const int tx = threadIdx.x & 15, ty = threadIdx.x >> 4;
  float acc[4][4] = {};
  for (int k0 = 0; k0 < 512; k0 += 64) {
    __syncthreads();
#pragma unroll
    for (int p = 0; p < 4; p++) {
      int r = ty + p * 16;
      float4 a = *(const float4*)&G [(size_t)(i0 + r) * 512 + k0 + tx * 4];
      float4 b = *(const float4*)&Bm[(size_t)(k0 + r) * 512 + j0 + tx * 4];
      *(float4*)&As[r][tx * 4] = a;
      *(float4*)&Bs[r][tx * 4] = b;
    }
    __syncthreads();
    for (int kk = 0; kk < 64; kk++) {
      float a0 = As[ty*4+0][kk], a1 = As[ty*4+1][kk], a2 = As[ty*4+2][kk], a3 = As[ty*4+3][kk];
      float4 bq = *(const float4*)&Bs[kk][tx * 4];
      acc[0][0] += a0*bq.x; acc[0][1] += a0*bq.y; acc[0][2] += a0*bq.z; acc[0][3] += a0*bq.w;
      acc[1][0] += a1*bq.x; acc[1][1] += a1*bq.y; acc[1][2] += a1*bq.z; acc[1][3] += a1*bq.w;
      acc[2][0] += a2*bq.x; acc[2][1] += a2*bq.y; acc[2][2] += a2*bq.z; acc[2][3] += a2*bq.w;
      acc[3][0] += a3*bq.x; acc[3][1] += a3*bq.y; acc[3][2] += a3*bq.z; acc[3][3] += a3*bq.w;
    }
  }
#pragma unroll
  for (int u = 0; u < 4; u++) {
    float4 o = make_float4(acc[u][0], acc[u][1], acc[u][2], acc[u][3]);
    *(float4*)&Cm[(size_t)(i0 + ty * 4 + u) * 512 + j0 + tx * 4] = o;
  }
}

// ---------------- norms ----------------
__global__ void k_norms(const float* __restrict__ Wq, const float* __restrict__ Tq,
                        const float* __restrict__ Wk, const float* __restrict__ Tk,
                        float* __restrict__ qn, float* __restrict__ kn)
{
  const int gw = (blockIdx.x * 256 + threadIdx.x) >> 6;
  const int lane = threadIdx.x & 63;
  const float* Wm = (gw < 512) ? Wq : Wk;
  const float* Tm = (gw < 512) ? Tq : Tk;
  const int c = gw & 511;
  float s = 0.f;
  for (int r = lane; r < 512; r += 64) s += Wm[(size_t)r * 512 + c] * Tm[(size_t)r * 512 + c];
  for (int off = 32; off > 0; off >>= 1) s += __shfl_down(s, off);
  if (lane == 0) {
    float n = sqrtf(fmaxf(s, 0.f));
    ((gw < 512) ? qn : kn)[c] = fmaxf(n, 1e-12f);
  }
}

// ---------------- per-head logits + softmax ----------------
__global__ __launch_bounds__(256) void k_attn(const float* __restrict__ Wk, const float* __restrict__ Tq,
    const float* __restrict__ qn, const float* __restrict__ kn,
    const float* __restrict__ rescale, float* __restrict__ attn)
{
  const int h = blockIdx.x, hd = h * 64;
  __shared__ float Ks[64][68];
  __shared__ float Qs[64][68];
  __shared__ float Ss[64][65];
  const int tx = threadIdx.x & 15, ty = threadIdx.x >> 4;
  float acc[4][4] = {};
  for (int k0 = 0; k0 < 512; k0 += 64) {
    __syncthreads();
#pragma unroll
    for (int p = 0; p < 4; p++) {
      int r = ty + p * 16;
      float4 a = *(const float4*)&Wk[(size_t)(k0 + r) * 512 + hd + tx * 4];
      float4 b = *(const float4*)&Tq[(size_t)(k0 + r) * 512 + hd + tx * 4];
      *(float4*)&Ks[r][tx * 4] = a;
      *(float4*)&Qs[r][tx * 4] = b;
    }
    __syncthreads();
    for (int kk = 0; kk < 64; kk++) {
      float a0 = Ks[kk][ty*4+0], a1 = Ks[kk][ty*4+1], a2 = Ks[kk][ty*4+2], a3 = Ks[kk][ty*4+3];
      float4 bq = *(const float4*)&Qs[kk][tx * 4];
      acc[0][0] += a0*bq.x; acc[0][1] += a0*bq.y; acc[0][2] += a0*bq.z; acc[0][3] += a0*bq.w;
      acc[1][0] += a1*bq.x; acc[1][1] += a1*bq.y; acc[1][2] += a1*bq.z; acc[1][3] += a1*bq.w;
      acc[2][0] += a2*bq.x; acc[2][1] += a2*bq.y; acc[2][2] += a2*bq.z; acc[2][3] += a2*bq.w;
      acc[3][0] += a3*bq.x; acc[3][1] += a3*bq.y; acc[3][2] += a3*bq.z; acc[3][3] += a3*bq.w;
    }
  }
#pragma unroll
  for (int u = 0; u < 4; u++)
#pragma unroll
    for (int v = 0; v < 4; v++)
      Ss[ty * 4 + u][tx * 4 + v] = acc[u][v];
  __syncthreads();
  if (threadIdx.x < 64) {
    const int i = threadIdx.x;
    const float sci = rescale[h] / kn[hd + i];
    float mx = -1e30f;
    for (int j = 0; j < 64; j++) {
      float L = Ss[i][j] * sci / qn[hd + j];
      Ss[i][j] = L;
      mx = fmaxf(mx, L);
    }
    float sum = 0.f;
    for (int j = 0; j < 64; j++) { float e = __expf(Ss[i][j] - mx); Ss[i][j] = e; sum += e; }
    float inv = 1.f / sum;
    for (int j = 0; j < 64; j++) attn[(size_t)h * 4096 + i * 64 + j] = Ss[i][j] * inv;
  }
}

// ---------------- fold attn into Wp ----------------
__global__ void k_w2t(const float* __restrict__ attn, const float* __restrict__ Wp, u16* __restrict__ W2T)
{
  const int h = blockIdx.x >> 3, e0 = (blockIdx.x & 7) * 64;
  __shared__ float As[64][65];
  for (int p = 0; p < 16; p++) {
    int idx = p * 256 + threadIdx.x;
    As[idx >> 6][idx & 63] = attn[(size_t)h * 4096 + idx];
  }
  __syncthreads();
  const int e = e0 + (threadIdx.x & 63);
  const int j4 = threadIdx.x >> 6;
  float s[16];
#pragma unroll
  for (int jj = 0; jj < 16; jj++) s[jj] = 0.f;
  for (int i = 0; i < 64; i++) {
    float wv_ = Wp[(size_t)(h * 64 + i) * 512 + e];
#pragma unroll
    for (int jj = 0; jj < 16; jj++) s[jj] += As[i][j4 * 16 + jj] * wv_;
  }
#pragma unroll
  for (int jj = 0; jj < 16; jj++)
    W2T[(size_t)e * 512 + h * 64 + j4 * 16 + jj] = f2bf(s[jj]);
}

// ---------------- SAR branch ----------------
__global__ void k_conv3(const float* __restrict__ sar, const float* __restrict__ w3,
                        const float* __restrict__ b3, float* __restrict__ a)
{
  const int oc = blockIdx.y;
  const int p = blockIdx.x * 256 + threadIdx.x;
  const int y = p >> 8, x = p & 255;
  float s = b3[oc];
#pragma unroll
  for (int ic = 0; ic < 2; ic++) {
    const float* img = sar + ic * 65536;
    const float* w = w3 + oc * 18 + ic * 9;
#pragma unroll
    for (int k = 0; k < 9; k++) {
      int yy = y + k / 3 - 1, xx = x + k % 3 - 1;
      if ((unsigned)yy < 256u && (unsigned)xx < 256u) s += w[k] * img[yy * 256 + xx];
    }
  }
  a[oc * 65536 + p] = s;
}

__global__ void k_bnstats(const float* __restrict__ a, const float* __restrict__ g,
                          const float* __restrict__ b, float* __restrict__ bnp)
{
  const int ch = blockIdx.x;
  const int tid = threadIdx.x;
  const float* src = a + ch * 65536;
  float s = 0.f, sq = 0.f;
  for (int i = tid; i < 65536; i += 256) { float v = src[i]; s += v; sq += v * v; }
  __shared__ float rs[256], rq[256];
  rs[tid] = s; rq[tid] = sq;
  __syncthreads();
  for (int o = 128; o > 0; o >>= 1) {
    if (tid < o) { rs[tid] += rs[tid + o]; rq[tid] += rq[tid + o]; }
    __syncthreads();
  }
  if (tid == 0) {
    float mu = rs[0] * (1.f / 65536.f);
    float var = rq[0] * (1.f / 65536.f) - mu * mu;
    float scale = g[ch] / sqrtf(var + 1e-5f);
    bnp[ch] = scale;
    bnp[2 + ch] = b[ch] - mu * scale;
  }
}

__global__ void k_sar2(const float* __restrict__ a, const float* __restrict__ bnp,
                       const float* __restrict__ sb, float* __restrict__ ss)
{
  const int p = blockIdx.x * 256 + threadIdx.x;
  const int y = p >> 8, x = p & 255;
  const float sc0 = bnp[0], sc1 = bnp[1], sh0 = bnp[2], sh1 = bnp[3];
  float bs[9];
  float bn0c = 0.f, bn1c = 0.f;
#pragma unroll
  for (int k = 0; k < 9; k++) {
    int yy = y + k / 3 - 1, xx = x + k % 3 - 1;
    float v0 = 0.f, v1 = 0.f;
    if ((unsigned)yy < 256u && (unsigned)xx < 256u) {
      int q = yy * 256 + xx;
      v0 = a[q] * sc0 + sh0;
      v1 = a[65536 + q] * sc1 + sh1;
    }
    bs[k] = v0 + v1;
    if (k == 4) { bn0c = v0; bn1c = v1; }
  }
  float gv = (bs[6] + 2.f * bs[7] + bs[8]) - (bs[0] + 2.f * bs[1] + bs[2]);
  float gh = (bs[2] + 2.f * bs[5] + bs[8]) - (bs[0] + 2.f * bs[3] + bs[6]);
  float s0 = gv + sb[0], s1 = gh + sb[1], s2 = gv + sb[2], s3 = gh + sb[3];
  ss[p]         = sqrtf(s0 * s0 + s1 * s1) + bn0c;
  ss[65536 + p] = sqrtf(s2 * s2 + s3 * s3) + bn1c;
}

// =====================================================================
// Mask via MFMA GEMM. mask = L1 + beta_c*(W(p)-wsum_c) + sigmoid(L2),
// L1/L2 linear in the 50-value patch; K=192 hi/lo-compensated bf16 GEMM.
// Epilogue stages mask (f32) through LDS so the VB gate is done with
// coalesced ushort8 RMW (16B/lane) instead of scalar u16 RMW.
// =====================================================================

// ---- k_dwprep: build BM [1024][192] bf16 and border tables TB [512][32] ----
__global__ void k_dwprep(const float* __restrict__ dw, const float* __restrict__ db,
                         const float* __restrict__ w2, const float* __restrict__ b2,
                         const float* __restrict__ w32, const float* __restrict__ b32,
                         u16* __restrict__ BM, float* __restrict__ TB)
{
  const int c = blockIdx.x * 256 + threadIdx.x;
  if (c >= 512) return;
  float d[25];
  float wsum = 0.f;
#pragma unroll
  for (int t = 0; t < 25; t++) { d[t] = dw[c * 25 + t]; wsum += d[t]; }
  const float a = w2[2 * c], b = w2[2 * c + 1], beta = b2[c];
  const float C1 = beta * (1.f + wsum) + db[c];

  u16* rL1 = BM + (size_t)((c >> 6) * 128 + (c & 63)) * 192;
  u16* rL2 = rL1 + (size_t)64 * 192;

#pragma unroll
  for (int k = 0; k < 64; k++) {
    float v1;
    if (k < 25)       v1 = a * (d[k] + (k == 12 ? 1.f : 0.f));
    else if (k < 50)  v1 = b * (d[k - 25] + (k == 37 ? 1.f : 0.f));
    else if (k == 63) v1 = C1;
    else              v1 = 0.f;
    u16 h = f2bf(v1); u16 l = f2bf(v1 - bf2f(h));
    rL1[k] = h; rL1[64 + k] = h; rL1[128 + k] = l;
  }
#pragma unroll
  for (int k = 0; k < 64; k++) {
    float v2 = 0.f;
    if (k < 50) {
      const int t = (k < 25) ? k : (k - 25);
      const int dy = t / 5 - 2, dx = t % 5 - 2;
      if (dy >= -1 && dy <= 1 && dx >= -1 && dx <= 1)
        v2 = w32[c * 18 + ((k < 25) ? 0 : 9) + (dy + 1) * 3 + (dx + 1)];
    }
    if (k == 63) v2 = b32[c];
    u16 h = f2bf(v2); u16 l = f2bf(v2 - bf2f(h));
    rL2[k] = h; rL2[64 + k] = h; rL2[128 + k] = l;
  }

  // border tables: W = wsum - T[mt] - B[mb] - L[ml] - R[mr] + corners
  float rs[5], cs[5];
#pragma unroll
  for (int i = 0; i < 5; i++) {
    rs[i] = d[i*5] + d[i*5+1] + d[i*5+2] + d[i*5+3] + d[i*5+4];
    cs[i] = d[i] + d[5+i] + d[10+i] + d[15+i] + d[20+i];
  }
  float* tb = TB + (size_t)c * 32;
  tb[0] = rs[0];  tb[1] = rs[0] + rs[1];          // T1, T2 (missing top rows)
  tb[2] = rs[4];  tb[3] = rs[3] + rs[4];          // B1, B2
  tb[4] = cs[0];  tb[5] = cs[0] + cs[1];          // L1, L2
  tb[6] = cs[4];  tb[7] = cs[3] + cs[4];          // R1, R2
  tb[8]  = d[0];           tb[9]  = d[0] + d[1];            // TL(1,1) TL(1,2)
  tb[10] = d[0] + d[5];    tb[11] = d[0] + d[1] + d[5] + d[6];
  tb[12] = d[4];           tb[13] = d[3] + d[4];            // TR
  tb[14] = d[4] + d[9];    tb[15] = d[3] + d[4] + d[8] + d[9];
  tb[16] = d[20];          tb[17] = d[20] + d[21];          // BL
  tb[18] = d[15] + d[20];  tb[19] = d[15] + d[16] + d[20] + d[21];
  tb[20] = d[24];          tb[21] = d[23] + d[24];          // BR
  tb[22] = d[19] + d[24];  tb[23] = d[18] + d[19] + d[23] + d[24];
#pragma unroll
  for (int i = 24; i < 32; i++) tb[i] = 0.f;
}

// ---- k_patch: build P [65536][192] bf16 patch matrix from SS ----
__global__ __launch_bounds__(256) void k_patch(const float* __restrict__ ss, u16* __restrict__ P)
{
  __shared__ float s0r[5][264];
  __shared__ float s1r[5][264];
  const int y = blockIdx.x;       // one image row per block
  const int tid = threadIdx.x;
  for (int i = tid; i < 1300; i += 256) {
    const int r = i / 260, col = i - r * 260;
    const int yy = y + r - 2, xx = col - 2;
    const bool in = ((unsigned)yy < 256u) & ((unsigned)xx < 256u);
    const int gp = yy * 256 + xx;
    s0r[r][col] = in ? ss[gp] : 0.f;
    s1r[r][col] = in ? ss[65536 + gp] : 0.f;
  }
  __syncthreads();
  const int x = tid;
  unsigned arr32[64];              // k[0..127]; k[128..191] is a copy of k[0..63]
#pragma unroll
  for (int i = 0; i < 64; i++) arr32[i] = 0u;
#define PUTK(k, v) arr32[(k) >> 1] |= ((unsigned)(v)) << (((k) & 1) * 16)
#pragma unroll
  for (int dy = 0; dy < 5; dy++)
#pragma unroll
    for (int dx = 0; dx < 5; dx++) {
      const int t = dy * 5 + dx;
      const float v0 = s0r[dy][x + dx];
      const float v1 = s1r[dy][x + dx];
      const u16 h0 = f2bf(v0); const u16 l0 = f2bf(v0 - bf2f(h0));
      const u16 h1 = f2bf(v1); const u16 l1 = f2bf(v1 - bf2f(h1));
      PUTK(t, h0);      PUTK(25 + t, h1);
      PUTK(64 + t, l0); PUTK(89 + t, l1);
    }
  PUTK(63, 0x3F80u);               // 1.0 for bias slot (block2 copy gives k191=1.0)
#undef PUTK
  unsigned* dst = (unsigned*)(P + (size_t)(y * 256 + x) * 192);
#pragma unroll
  for (int i = 0; i < 16; i++)
    *(uint4*)(dst + i * 4) = *(const uint4*)(arr32 + i * 4);
#pragma unroll
  for (int i = 0; i < 8; i++)
    *(uint4*)(dst + 64 + i * 4) = *(const uint4*)(arr32 + i * 4);
}

// ---- k_maskmm: C = P @ BM^T fused with sigmoid/border/V-gate, in-place VB ----
// Tile: M=128 px, N=128 (64 ch: n<64 -> L1, n>=64 -> L2), K=192 (no outer loop).
// 4 waves stacked in M (wave tile 32x128) so each lane holds L1 and L2 of the
// SAME channel. Mask staged f32 in LDS; VB gated with coalesced ushort8 RMW.
__global__ __launch_bounds__(256) void k_maskmm(
    const u16* __restrict__ P, const u16* __restrict__ BM,
    const float* __restrict__ TB, const float* __restrict__ beta_p,
    u16* __restrict__ VB)
{
  // pool: staging (16 KiB) aliased over mask tile [128][68] f32 (34 KiB)
  __shared__ __align__(16) float lds_pool[128 * 68];
  uint4* smem = (uint4*)lds_pool;
  const int tid  = threadIdx.x;
  const int lane = tid & 63;
  const int wv   = tid >> 6;
  const int m0   = blockIdx.x * 128;
  const int g    = blockIdx.y;          // channel group (64 ch)

  const int q0 = tid, q1 = tid + 256;
  const size_t arow0 = (size_t)(m0 + (q0 >> 2)) * 192 + (q0 & 3) * 8;
  const size_t arow1 = (size_t)(m0 + (q1 >> 2)) * 192 + (q1 & 3) * 8;
  const size_t brow0 = (size_t)(g * 128 + (q0 >> 2)) * 192 + (q0 & 3) * 8;
  const size_t brow1 = (size_t)(g * 128 + (q1 >> 2)) * 192 + (q1 & 3) * 8;

  f32x4 acc[2][8] = {};
  const char* lAc = (const char*)smem;
  const char* lBc = (const char*)(smem + 512);
  const int ko = (lane >> 4) * 16;
  const int ma = lane & 15;

  for (int k0 = 0; k0 < 192; k0 += 32) {
    __syncthreads();
    GLOAD_LDS16(&P[arow0 + k0],  &smem[q0]);
    GLOAD_LDS16(&P[arow1 + k0],  &smem[q1]);
    GLOAD_LDS16(&BM[brow0 + k0], &smem[512 + q0]);
    GLOAD_LDS16(&BM[brow1 + k0], &smem[512 + q1]);
    __syncthreads();
    short8 af[2], bfr[8];
#pragma unroll
    for (int mt = 0; mt < 2; mt++)
      af[mt] = *(const short8*)(lAc + (wv * 32 + mt * 16 + ma) * 64 + ko);
#pragma unroll
    for (int nt = 0; nt < 8; nt++)
      bfr[nt] = *(const short8*)(lBc + (nt * 16 + ma) * 64 + ko);
#pragma unroll
    for (int mt = 0; mt < 2; mt++)
#pragma unroll
      for (int nt = 0; nt < 8; nt++)
        acc[mt][nt] = __builtin_amdgcn_mfma_f32_16x16x32_bf16(af[mt], bfr[nt], acc[mt][nt], 0, 0, 0);
  }

  __syncthreads();     // all waves done with staging reads; pool reused as mask tile
  const int col = lane & 15, rq = (lane >> 4) * 4;
  const int y   = m0 >> 8;                       // block covers half a row: y uniform
  const int mty = (y < 2) ? (2 - y) : 0;
  const int mby = (y > 253) ? (y - 253) : 0;
#pragma unroll
  for (int mt = 0; mt < 2; mt++) {
#pragma unroll
    for (int nt = 0; nt < 4; nt++) {
      const int ch = g * 64 + nt * 16 + col;
#pragma unroll
      for (int r = 0; r < 4; r++) {
        const int pxl = wv * 32 + mt * 16 + rq + r;      // 0..127
        const float L1 = acc[mt][nt][r];
        const float L2 = acc[mt][nt + 4][r];
        const int x  = (m0 + pxl) & 255;
        const int ml = (x < 2) ? (2 - x) : 0;
        const int mr = (x > 253) ? (x - 253) : 0;
        float wc = 0.f;
        if (mty | mby | ml | mr) {
          const float* tb = &TB[(size_t)ch * 32];
          float W = 0.f;
          if (mty) W -= tb[mty - 1];
          if (mby) W -= tb[2 + mby - 1];
          if (ml)  W -= tb[4 + ml - 1];
          if (mr)  W -= tb[6 + mr - 1];
          if (mty && ml) W += tb[8  + (mty - 1) * 2 + (ml - 1)];
          if (mty && mr) W += tb[12 + (mty - 1) * 2 + (mr - 1)];
          if (mby && ml) W += tb[16 + (mby - 1) * 2 + (ml - 1)];
          if (mby && mr) W += tb[20 + (mby - 1) * 2 + (mr - 1)];
          wc = beta_p[ch] * W;
        }
        const float sig = 1.f / (1.f + __expf(-L2));
        lds_pool[pxl * 68 + nt * 16 + col] = L1 + wc + sig;
      }
    }
  }
  __syncthreads();
  // coalesced gate: 4 chunks/thread, chunk = 8 ch (16 B) of one pixel row
#pragma unroll
  for (int k = 0; k < 4; k++) {
    const int cid = k * 256 + tid;
    const int pxl = cid >> 3;              // 0..127
    const int cp  = (cid & 7) * 8;         // 0..56
    const float4 ma0 = *(const float4*)&lds_pool[pxl * 68 + cp];
    const float4 ma1 = *(const float4*)&lds_pool[pxl * 68 + cp + 4];
    u16* vp = &VB[(size_t)(m0 + pxl) * 512 + g * 64 + cp];
    short8 vv = *(const short8*)vp;
    short8 o;
    o[0] = (short)f2bf(bf2f((u16)vv[0]) * ma0.x);
    o[1] = (short)f2bf(bf2f((u16)vv[1]) * ma0.y);
    o[2] = (short)f2bf(bf2f((u16)vv[2]) * ma0.z);
    o[3] = (short)f2bf(bf2f((u16)vv[3]) * ma0.w);
    o[4] = (short)f2bf(bf2f((u16)vv[4]) * ma1.x);
    o[5] = (short)f2bf(bf2f((u16)vv[5]) * ma1.y);
    o[6] = (short)f2bf(bf2f((u16)vv[6]) * ma1.z);
    o[7] = (short)f2bf(bf2f((u16)vv[7]) * ma1.w);
    *(short8*)vp = o;
  }
}

// =====================================================================
// Vectorized depthwise 3x3 (plane layout). Wave = 16 x-subgroups x 4 channels;
// lane loads ushort4 per row, halo via shfl; edge subgroups do predicated u16 load.
// =====================================================================
DEVFN void dw3x3_row4(const u16* plane, int y, int x0, int sub,
                      const float* w9, float& s0, float& s1, float& s2, float& s3)
{
#pragma unroll
  for (int r = 0; r < 3; r++) {
    int yy = y + r - 1;
    if ((unsigned)yy < 256u) {       // block-uniform branch
      const int base = yy * 256 + x0 + sub * 4;
      ushort4 p = *(const ushort4*)&plane[base];
      float v0 = bf2f(p.x), v1 = bf2f(p.y), v2 = bf2f(p.z), v3 = bf2f(p.w);
      float lf = __shfl_up(v3, 1);
      float rt = __shfl_down(v0, 1);
      if (sub == 0)  lf = (x0 > 0)   ? bf2f(plane[yy * 256 + x0 - 1])  : 0.f;
      if (sub == 15) rt = (x0 < 192) ? bf2f(plane[yy * 256 + x0 + 64]) : 0.f;
      const float wa = w9[r * 3], wb = w9[r * 3 + 1], wc = w9[r * 3 + 2];
      s0 += wa * lf + wb * v0 + wc * v1;
      s1 += wa * v0 + wb * v1 + wc * v2;
      s2 += wa * v1 + wb * v2 + wc * v3;
      s3 += wa * v2 + wb * v3 + wc * rt;
    }
  }
}

// pe1: dconv3x3(VT) -> exact GELU -> GT (plane layout, vectorized)
__global__ __launch_bounds__(256) void k_pe1v(const u16* __restrict__ vt,
    const float* __restrict__ w, u16* __restrict__ gt)
{
  const int t = blockIdx.x;
  const int y = t >> 2, x0 = (t & 3) * 64;
  const int cg = blockIdx.y * 64;
  const int lane = threadIdx.x & 63, wvq = threadIdx.x >> 6;
  const int sub = lane & 15, chq = lane >> 4;
#pragma unroll
  for (int i = 0; i < 4; i++) {
    const int c = cg + wvq * 16 + i * 4 + chq;
    const u16* plane = vt + (size_t)c * 65536;
    float w9[9];
#pragma unroll
    for (int k = 0; k < 9; k++) w9[k] = w[c * 9 + k];
    float s0 = 0.f, s1 = 0.f, s2 = 0.f, s3 = 0.f;
    dw3x3_row4(plane, y, x0, sub, w9, s0, s1, s2, s3);
    const float ksc = 0.70710678118654752f;
    s0 = 0.5f * s0 * (1.f + erff(s0 * ksc));
    s1 = 0.5f * s1 * (1.f + erff(s1 * ksc));
    s2 = 0.5f * s2 * (1.f + erff(s2 * ksc));
    s3 = 0.5f * s3 * (1.f + erff(s3 * ksc));
    ushort4 o; o.x = f2bf(s0); o.y = f2bf(s1); o.z = f2bf(s2); o.w = f2bf(s3);
    *(ushort4*)&gt[(size_t)c * 65536 + y * 256 + x0 + sub * 4] = o;
  }
}

// pe2: dconv3x3(GT), LDS transpose (conflict-free), float4 RMW add into out[n][c]
__global__ __launch_bounds__(256) void k_pe2v(const u16* __restrict__ gt,
    const float* __restrict__ w, float* __restrict__ out)
{
  __shared__ float tile[64][65];
  const int t = blockIdx.x;
  const int y = t >> 2, x0 = (t & 3) * 64;
  const int cg = blockIdx.y * 64;
  const int lane = threadIdx.x & 63, wvq = threadIdx.x >> 6;
  const int sub = lane & 15, chq = lane >> 4;
#pragma unroll
  for (int i = 0; i < 4; i++) {
    const int cl = wvq * 16 + i * 4 + chq;
    const int c = cg + cl;
    const u16* plane = gt + (size_t)c * 65536;
    float w9[9];
#pragma unroll
    for (int k = 0; k < 9; k++) w9[k] = w[c * 9 + k];
    float s0 = 0.f, s1 = 0.f, s2 = 0.f, s3 = 0.f;
    dw3x3_row4(plane, y, x0, sub, w9, s0, s1, s2, s3);
    tile[cl][sub * 4 + 0] = s0;
    tile[cl][sub * 4 + 1] = s1;
    tile[cl][sub * 4 + 2] = s2;
    tile[cl][sub * 4 + 3] = s3;
  }
  __syncthreads();
#pragma unroll
  for (int k = 0; k < 4; k++) {
    const int idx = k * 256 + threadIdx.x;
    const int q = idx & 15, pl = idx >> 4;
    float4 add = make_float4(tile[q * 4 + 0][pl], tile[q * 4 + 1][pl],
                             tile[q * 4 + 2][pl], tile[q * 4 + 3][pl]);
    float* op = &out[(size_t)(y * 256 + x0 + pl) * 512 + cg + q * 4];
    float4 o = *(float4*)op;
    o.x += add.x; o.y += add.y; o.z += add.z; o.w += add.w;
    *(float4*)op = o;
  }
}

// =====================================================================
extern "C" void kernel_launch(void* const* d_in, const int* in_sizes, int n_in,
                              void* d_out, int out_size, void* d_ws, size_t ws_size,
                              hipStream_t stream)
{
  (void)in_sizes; (void)n_in; (void)out_size;
  const float* x    = (const float*)d_in[0];
  const float* sar  = (const float*)d_in[1];
  const float* Wq   = (const float*)d_in[2];
  const float* Wk   = (const float*)d_in[3];
  const float* Wv   = (const float*)d_in[4];
  const float* resc = (const float*)d_in[5];
  const float* Wp   = (const float*)d_in[6];
  const float* bp   = (const float*)d_in[7];
  const float* pe1w = (const float*)d_in[8];
  const float* pe2w = (const float*)d_in[9];
  const float* w3   = (const float*)d_in[10];
  const float* b3   = (const float*)d_in[11];
  const float* bng  = (const float*)d_in[12];
  const float* bnb  = (const float*)d_in[13];
  const float* sb   = (const float*)d_in[14];
  const float* w2c  = (const float*)d_in[15];
  const float* b2c  = (const float*)d_in[16];
  const float* w32  = (const float*)d_in[17];
  const float* b32  = (const float*)d_in[18];
  const float* dw   = (const float*)d_in[19];
  const float* db   = (const float*)d_in[20];
  float* out = (float*)d_out;

  if (ws_size < WS_NEEDED)
    fprintf(stderr, "MS_MSA: workspace too small: have %zu need %zu\n", ws_size, WS_NEEDED);

  char* ws = (char*)d_ws;
  u16* XB    = (u16*)(ws + OFF_XB);
  u16* XBT   = (u16*)(ws + OFF_XBT);
  u16* VB    = (u16*)(ws + OFF_VB);
  u16* VT    = (u16*)(ws + OFF_VT);
  float* GPART = (float*)(ws + OFF_GPART);
  float* G     = (float*)(ws + OFF_G);
  float* TQ    = (float*)(ws + OFF_TQ);
  float* TK    = (float*)(ws + OFF_TK);
  u16* WVT   = (u16*)(ws + OFF_WVT);
  u16* W2T   = (u16*)(ws + OFF_W2T);
  float* ASAR = (float*)(ws + OFF_ASAR);
  float* SS   = (float*)(ws + OFF_SS);
  float* BNP  = (float*)(ws + OFF_BNP);
  float* QN   = (float*)(ws + OFF_QN);
  float* KN   = (float*)(ws + OFF_KN);
  float* ATTN = (float*)(ws + OFF_ATTN);
  u16*  BM   = (u16*)(ws + OFF_BM);
  float* TBt  = (float*)(ws + OFF_TB);
  u16* GT  = XBT;                 // alias: XBT dead after Gram
  u16* P   = (u16*)(ws + OFF_GPART);  // alias: GPART dead after k_reduce_g

  // --- x -> bf16 (row + transposed) ---
  k_cast_transpose<<<dim3(1024, 8), 256, 0, stream>>>(x, XB, XBT);
  // --- G = X^T X ---
  gemm_bt<1><<<dim3(4, 4, GSPLIT), 256, 0, stream>>>(XBT, NTOK, XBT, NTOK, GKLEN, GPART, nullptr);
  k_reduce_g<<<1024, 256, 0, stream>>>(GPART, G);
  // --- v_inp = x @ Wv ---
  k_transpose_w<<<dim3(8, 8), 256, 0, stream>>>(Wv, WVT);
  gemm_bt<0><<<dim3(512, 4), 256, 0, stream>>>(XB, 512, WVT, 512, 512, VB, nullptr);
  k_tbf16<<<dim3(1024, 8), 256, 0, stream>>>(VB, VT, 65536, 512);   // VT = ungated v^T for pe1
  // --- attention stats ---
  k_gw<<<dim3(8, 8, 2), 256, 0, stream>>>(G, Wq, Wk, TQ, TK);
  k_norms<<<256, 256, 0, stream>>>(Wq, TQ, Wk, TK, QN, KN);
  k_attn<<<8, 256, 0, stream>>>(Wk, TQ, QN, KN, resc, ATTN);
  k_w2t<<<64, 256, 0, stream>>>(ATTN, Wp, W2T);
  // --- SAR branch ---
  k_conv3<<<dim3(256, 2), 256, 0, stream>>>(sar, w3, b3, ASAR);
  k_bnstats<<<2, 256, 0, stream>>>(ASAR, bng, bnb, BNP);
  k_sar2<<<256, 256, 0, stream>>>(ASAR, BNP, sb, SS);
  // --- mask via compensated bf16 MFMA GEMM, gate V in-place ([n][c]) ---
  k_dwprep<<<2, 256, 0, stream>>>(dw, db, w2c, b2c, w32, b32, BM, TBt);
  k_patch<<<256, 256, 0, stream>>>(SS, P);
  k_maskmm<<<dim3(512, 8), 256, 0, stream>>>(P, BM, TBt, b2c, VB);
  // --- out = (v*mask) @ W2 + bp ---
  gemm_bt<2><<<dim3(512, 4), 256, 0, stream>>>(VB, 512, W2T, 512, 512, out, bp);
  // --- positional branch (vectorized) ---
  k_pe1v<<<dim3(1024, 8), 256, 0, stream>>>(VT, pe1w, GT);
  k_pe2v<<<dim3(1024, 8), 256, 0, stream>>>(GT, pe2w, out);
}

// Round 3
// 911.023 us; speedup vs baseline: 1.0728x; 1.0182x over previous
//
#include <hip/hip_runtime.h>
#include <cstdint>
#include <cstdio>

typedef unsigned short u16;
typedef __attribute__((ext_vector_type(8))) short short8;   // 8 bf16 (4 VGPRs)
typedef __attribute__((ext_vector_type(4))) float f32x4;

#define DEVFN __device__ __forceinline__

DEVFN u16 f2bf(float f){ union{float f; unsigned u;} v; v.f=f; unsigned r = v.u + 0x7fffu + ((v.u>>16)&1u); return (u16)(r>>16); }
DEVFN float bf2f(u16 h){ union{unsigned u; float f;} v; v.u = ((unsigned)h)<<16; return v.f; }

// async global->LDS, 16B per lane (dwordx4). LDS dest must be wave-uniform base + lane*16.
#define GLOAD_LDS16(gp, lp) __builtin_amdgcn_global_load_lds( \
    (const __attribute__((address_space(1))) void*)(gp), \
    (__attribute__((address_space(3))) void*)(lp), 16, 0, 0)

// ---------------- problem constants ----------------
static constexpr int NTOK = 65536;   // H*W
static constexpr int GSPLIT = 32;    // split-K slabs for Gram
static constexpr int GKLEN  = NTOK / GSPLIT;

// ---------------- workspace layout (bytes) ----------------
static constexpr size_t MB = 1024 * 1024;
static constexpr size_t OFF_XB    = 0;          // bf16 x  [n][c]    64 MiB   (alias: PEB after gemm_v)
static constexpr size_t OFF_XBT   = 64 * MB;    // bf16 x^T [c][n]   64 MiB   (alias: GT)
static constexpr size_t OFF_VB    = 128 * MB;   // bf16 v_inp [n][c] 64 MiB   (gated in-place by k_maskmm)
static constexpr size_t OFF_VT    = 192 * MB;   // bf16 v^T [c][n]   64 MiB
static constexpr size_t OFF_GPART = 256 * MB;   // fp32 [32][512][512] 32 MiB (alias: P patch matrix 25.2 MiB)
static constexpr size_t OFF_G     = 288 * MB;
static constexpr size_t OFF_TQ    = 289 * MB;
static constexpr size_t OFF_TK    = 290 * MB;
static constexpr size_t OFF_WVT   = 291 * MB;            // bf16 Wv^T
static constexpr size_t OFF_W2T   = 291 * MB + 524288;   // bf16 W2^T
static constexpr size_t OFF_ASAR  = 292 * MB;            // fp32 [2][65536]
static constexpr size_t OFF_SS    = 292 * MB + 524288;   // fp32 [2][65536]
static constexpr size_t OFF_BNP   = 293 * MB;
static constexpr size_t OFF_QN    = 293 * MB + 4096;
static constexpr size_t OFF_KN    = 293 * MB + 8192;
static constexpr size_t OFF_ATTN  = 293 * MB + 12288;    // fp32 [8][64][64] = 128 KiB
static constexpr size_t OFF_BM    = 293 * MB + 262144;   // bf16 [1024][192] mask-GEMM weights (384 KiB)
static constexpr size_t OFF_TB    = 293 * MB + 786432;   // fp32 [512][32] border tables (64 KiB)
static constexpr size_t WS_NEEDED = 294 * MB;

// =====================================================================
// bf16 MFMA GEMM: C[M][512] = A[M][K] * B with B stored as [N][K] (B^T).
// 128x128 tile, 4 waves 2x2, wave = 64x64 via 4x4 16x16x32 frags.
// Staging via global_load_lds width=16 (m97 pattern).
// MODE 0: bf16 C. MODE 1: fp32 partial slab (split-K, z).
// MODE 3: fp32 C + bias + bf16 PE add (final output, single writer of out).
// =====================================================================
template<int MODE>
__global__ __launch_bounds__(256) void gemm_bt(
    const u16* __restrict__ A, int lda,
    const u16* __restrict__ B, int ldb,
    int klen,
    void* __restrict__ Cout,
    const float* __restrict__ bias,
    const u16* __restrict__ pe)
{
  __shared__ uint4 smem[1024];  // A tile [0..511] = 128x32 bf16 (64B rows); B tile [512..1023]
  const int tid  = threadIdx.x;
  const int lane = tid & 63;
  const int wv   = tid >> 6;
  const int wm   = (wv >> 1) * 64;
  const int wn   = (wv & 1) * 64;
  const int m0   = blockIdx.x * 128;
  const int n0   = blockIdx.y * 128;
  const int kb   = blockIdx.z * klen;

  const int q0 = tid, q1 = tid + 256;
  const size_t arow0 = (size_t)(m0 + (q0 >> 2)) * lda + (q0 & 3) * 8;
  const size_t arow1 = (size_t)(m0 + (q1 >> 2)) * lda + (q1 & 3) * 8;
  const size_t brow0 = (size_t)(n0 + (q0 >> 2)) * ldb + (q0 & 3) * 8;
  const size_t brow1 = (size_t)(n0 + (q1 >> 2)) * ldb + (q1 & 3) * 8;

  f32x4 acc[4][4] = {};
  const char* lAc = (const char*)smem;
  const char* lBc = (const char*)(smem + 512);
  const int ko = (lane >> 4) * 16;
  const int ma = lane & 15;

  for (int k0 = kb; k0 < kb + klen; k0 += 32) {
    __syncthreads();                      // all waves done reading previous tile
    GLOAD_LDS16(&A[arow0 + k0], &smem[q0]);
    GLOAD_LDS16(&A[arow1 + k0], &smem[q1]);
    GLOAD_LDS16(&B[brow0 + k0], &smem[512 + q0]);
    GLOAD_LDS16(&B[brow1 + k0], &smem[512 + q1]);
    __syncthreads();                      // drains vmcnt -> LDS data visible
    short8 af[4], bfr[4];
#pragma unroll
    for (int mt = 0; mt < 4; mt++)
      af[mt] = *(const short8*)(lAc + (wm + mt * 16 + ma) * 64 + ko);
#pragma unroll
    for (int nt = 0; nt < 4; nt++)
      bfr[nt] = *(const short8*)(lBc + (wn + nt * 16 + ma) * 64 + ko);
#pragma unroll
    for (int mt = 0; mt < 4; mt++)
#pragma unroll
      for (int nt = 0; nt < 4; nt++)
        acc[mt][nt] = __builtin_amdgcn_mfma_f32_16x16x32_bf16(af[mt], bfr[nt], acc[mt][nt], 0, 0, 0);
  }

  const int col = lane & 15;
  const int rq  = (lane >> 4) * 4;
  float* Cf = (float*)Cout;
  u16*   Ch = (u16*)Cout;
  if (MODE == 1) Cf += (size_t)blockIdx.z * 512 * 512;
#pragma unroll
  for (int mt = 0; mt < 4; mt++) {
#pragma unroll
    for (int nt = 0; nt < 4; nt++) {
      const int mbase = m0 + wm + mt * 16 + rq;
      const int nn    = n0 + wn + nt * 16 + col;
#pragma unroll
      for (int r = 0; r < 4; r++) {
        float vv = acc[mt][nt][r];
        size_t idx = (size_t)(mbase + r) * 512 + nn;
        if (MODE == 0)      Ch[idx] = f2bf(vv);
        else if (MODE == 1) Cf[idx] = vv;
        else                Cf[idx] = vv + bias[nn] + bf2f(pe[idx]);
      }
    }
  }
}

// ---------------- x fp32 [n][512] -> bf16 xb [n][512] and xbT [512][n] ----------------
__global__ void k_cast_transpose(const float* __restrict__ x, u16* __restrict__ xb, u16* __restrict__ xbT)
{
  __shared__ u16 tile[64][72];
  const int t0 = blockIdx.x * 64, c0 = blockIdx.y * 64;
  const int tx = threadIdx.x & 15, ty = threadIdx.x >> 4;
#pragma unroll
  for (int p = 0; p < 4; p++) {
    int t = ty + p * 16;
    float4 v = *(const float4*)&x[(size_t)(t0 + t) * 512 + c0 + tx * 4];
    ushort4 u; u.x = f2bf(v.x); u.y = f2bf(v.y); u.z = f2bf(v.z); u.w = f2bf(v.w);
    *(ushort4*)&xb[(size_t)(t0 + t) * 512 + c0 + tx * 4] = u;
    tile[t][tx*4+0] = u.x; tile[t][tx*4+1] = u.y; tile[t][tx*4+2] = u.z; tile[t][tx*4+3] = u.w;
  }
  __syncthreads();
#pragma unroll
  for (int p = 0; p < 4; p++) {
    int c = ty + p * 16;
    ushort4 u;
    u.x = tile[tx*4+0][c]; u.y = tile[tx*4+1][c]; u.z = tile[tx*4+2][c]; u.w = tile[tx*4+3][c];
    *(ushort4*)&xbT[(size_t)(c0 + c) * 65536 + t0 + tx * 4] = u;
  }
}

// ---------------- generic bf16 tiled transpose: src[srows][scols] -> dst[scols][srows] ----------------
__global__ void k_tbf16(const u16* __restrict__ src, u16* __restrict__ dst, int srows, int scols)
{
  __shared__ u16 tile[64][72];
  const int r0 = blockIdx.x * 64, c0v = blockIdx.y * 64;
  const int tx = threadIdx.x & 15, ty = threadIdx.x >> 4;
#pragma unroll
  for (int p = 0; p < 4; p++) {
    int r = ty + p * 16;
    ushort4 u = *(const ushort4*)&src[(size_t)(r0 + r) * scols + c0v + tx * 4];
    tile[r][tx*4+0] = u.x; tile[r][tx*4+1] = u.y; tile[r][tx*4+2] = u.z; tile[r][tx*4+3] = u.w;
  }
  __syncthreads();
#pragma unroll
  for (int p = 0; p < 4; p++) {
    int c = ty + p * 16;
    ushort4 u;
    u.x = tile[tx*4+0][c]; u.y = tile[tx*4+1][c]; u.z = tile[tx*4+2][c]; u.w = tile[tx*4+3][c];
    *(ushort4*)&dst[(size_t)(c0v + c) * srows + r0 + tx * 4] = u;
  }
}

// ---------------- W fp32 [512][512] -> bf16 W^T ----------------
__global__ void k_transpose_w(const float* __restrict__ Wsrc, u16* __restrict__ WT)
{
  __shared__ u16 tile[64][72];
  const int k0 = blockIdx.x * 64, n0 = blockIdx.y * 64;
  const int tx = threadIdx.x & 15, ty = threadIdx.x >> 4;
#pragma unroll
  for (int p = 0; p < 4; p++) {
    int t = ty + p * 16;
    float4 v = *(const float4*)&Wsrc[(size_t)(k0 + t) * 512 + n0 + tx * 4];
    tile[t][tx*4+0] = f2bf(v.x); tile[t][tx*4+1] = f2bf(v.y);
    tile[t][tx*4+2] = f2bf(v.z); tile[t][tx*4+3] = f2bf(v.w);
  }
  __syncthreads();
#pragma unroll
  for (int p = 0; p < 4; p++) {
    int c = ty + p * 16;
    ushort4 u;
    u.x = tile[tx*4+0][c]; u.y = tile[tx*4+1][c]; u.z = tile[tx*4+2][c]; u.w = tile[tx*4+3][c];
    *(ushort4*)&WT[(size_t)(n0 + c) * 512 + k0 + tx * 4] = u;
  }
}

// ---------------- reduce Gram partials ----------------
__global__ void k_reduce_g(const float* __restrict__ part, float* __restrict__ G)
{
  const int i = blockIdx.x * 256 + threadIdx.x;
  float s = 0.f;
  for (int z = 0; z < GSPLIT; z++) s += part[(size_t)z * 262144 + i];
  G[i] = s;
}

// ---------------- Tq = G@Wq, Tk = G@Wk ----------------
__global__ __launch_bounds__(256) void k_gw(const float* __restrict__ G,
    const float* __restrict__ Wq, const float* __restrict__ Wk,
    float* __restrict__ Tq, float* __restrict__ Tk)
{
  const float* Bm = blockIdx.z ? Wk : Wq;
  float* Cm = blockIdx.z ? Tk : Tq;
  __shared__ float As[64][68];
  __shared__ float Bs[64][68];
  const int i0 = blockIdx.x * 64, j0 = blockIdx.y * 64;
  const int tx = threadIdx.x & 15, ty = threadIdx.x >> 4;
  float acc[4][4] = {};
  for (int k0 = 0; k0 < 512; k0 += 64) {
    __syncthreads();
#pragma unroll
    for (int p = 0; p < 4; p++) {
      int r = ty + p * 16;
      float4 a = *(const float4*)&G [(size_t)(i0 + r) * 512 + k0 + tx * 4];
      float4 b = *(const float4*)&Bm[(size_t)(k0 + r) * 512 + j0 + tx * 4];
      *(float4*)&As[r][tx * 4] = a;
      *(float4*)&Bs[r][tx * 4] = b;
    }
    __syncthreads();
    for (int kk = 0; kk < 64; kk++) {
      float a0 = As[ty*4+0][kk], a1 = As[ty*4+1][kk], a2 = As[ty*4+2][kk], a3 = As[ty*4+3][kk];
      float4 bq = *(const float4*)&Bs[kk][tx * 4];
      acc[0][0] += a0*bq.x; acc[0][1] += a0*bq.y; acc[0][2] += a0*bq.z; acc[0][3] += a0*bq.w;
      acc[1][0] += a1*bq.x; acc[1][1] += a1*bq.y; acc[1][2] += a1*bq.z; acc[1][3] += a1*bq.w;
      acc[2][0] += a2*bq.x; acc[2][1] += a2*bq.y; acc[2][2] += a2*bq.z; acc[2][3] += a2*bq.w;
      acc[3][0] += a3*bq.x; acc[3][1] += a3*bq.y; acc[3][2] += a3*bq.z; acc[3][3] += a3*bq.w;
    }
  }
#pragma unroll
  for (int u = 0; u < 4; u++) {
    float4 o = make_float4(acc[u][0], acc[u][1], acc[u][2], acc[u][3]);
    *(float4*)&Cm[(size_t)(i0 + ty * 4 + u) * 512 + j0 + tx * 4] = o;
  }
}

// ---------------- norms ----------------
__global__ void k_norms(const float* __restrict__ Wq, const float* __restrict__ Tq,
                        const float* __restrict__ Wk, const float* __restrict__ Tk,
                        float* __restrict__ qn, float* __restrict__ kn)
{
  const int gw = (blockIdx.x * 256 + threadIdx.x) >> 6;
  const int lane = threadIdx.x & 63;
  const float* Wm = (gw < 512) ? Wq : Wk;
  const float* Tm = (gw < 512) ? Tq : Tk;
  const int c = gw & 511;
  float s = 0.f;
  for (int r = lane; r < 512; r += 64) s += Wm[(size_t)r * 512 + c] * Tm[(size_t)r * 512 + c];
  for (int off = 32; off > 0; off >>= 1) s += __shfl_down(s, off);
  if (lane == 0) {
    float n = sqrtf(fmaxf(s, 0.f));
    ((gw < 512) ? qn : kn)[c] = fmaxf(n, 1e-12f);
  }
}

// ---------------- per-head logits + softmax ----------------
__global__ __launch_bounds__(256) void k_attn(const float* __restrict__ Wk, const float* __restrict__ Tq,
    const float* __restrict__ qn, const float* __restrict__ kn,
    const float* __restrict__ rescale, float* __restrict__ attn)
{
  const int h = blockIdx.x, hd = h * 64;
  __shared__ float Ks[64][68];
  __shared__ float Qs[64][68];
  __shared__ float Ss[64][65];
  const int tx = threadIdx.x & 15, ty = threadIdx.x >> 4;
  float acc[4][4] = {};
  for (int k0 = 0; k0 < 512; k0 += 64) {
    __syncthreads();
#pragma unroll
    for (int p = 0; p < 4; p++) {
      int r = ty + p * 16;
      float4 a = *(const float4*)&Wk[(size_t)(k0 + r) * 512 + hd + tx * 4];
      float4 b = *(const float4*)&Tq[(size_t)(k0 + r) * 512 + hd + tx * 4];
      *(float4*)&Ks[r][tx * 4] = a;
      *(float4*)&Qs[r][tx * 4] = b;
    }
    __syncthreads();
    for (int kk = 0; kk < 64; kk++) {
      float a0 = Ks[kk][ty*4+0], a1 = Ks[kk][ty*4+1], a2 = Ks[kk][ty*4+2], a3 = Ks[kk][ty*4+3];
      float4 bq = *(const float4*)&Qs[kk][tx * 4];
      acc[0][0] += a0*bq.x; acc[0][1] += a0*bq.y; acc[0][2] += a0*bq.z; acc[0][3] += a0*bq.w;
      acc[1][0] += a1*bq.x; acc[1][1] += a1*bq.y; acc[1][2] += a1*bq.z; acc[1][3] += a1*bq.w;
      acc[2][0] += a2*bq.x; acc[2][1] += a2*bq.y; acc[2][2] += a2*bq.z; acc[2][3] += a2*bq.w;
      acc[3][0] += a3*bq.x; acc[3][1] += a3*bq.y; acc[3][2] += a3*bq.z; acc[3][3] += a3*bq.w;
    }
  }
#pragma unroll
  for (int u = 0; u < 4; u++)
#pragma unroll
    for (int v = 0; v < 4; v++)
      Ss[ty * 4 + u][tx * 4 + v] = acc[u][v];
  __syncthreads();
  if (threadIdx.x < 64) {
    const int i = threadIdx.x;
    const float sci = rescale[h] / kn[hd + i];
    float mx = -1e30f;
    for (int j = 0; j < 64; j++) {
      float L = Ss[i][j] * sci / qn[hd + j];
      Ss[i][j] = L;
      mx = fmaxf(mx, L);
    }
    float sum = 0.f;
    for (int j = 0; j < 64; j++) { float e = __expf(Ss[i][j] - mx); Ss[i][j] = e; sum += e; }
    float inv = 1.f / sum;
    for (int j = 0; j < 64; j++) attn[(size_t)h * 4096 + i * 64 + j] = Ss[i][j] * inv;
  }
}

// ---------------- fold attn into Wp ----------------
__global__ void k_w2t(const float* __restrict__ attn, const float* __restrict__ Wp, u16* __restrict__ W2T)
{
  const int h = blockIdx.x >> 3, e0 = (blockIdx.x & 7) * 64;
  __shared__ float As[64][65];
  for (int p = 0; p < 16; p++) {
    int idx = p * 256 + threadIdx.x;
    As[idx >> 6][idx & 63] = attn[(size_t)h * 4096 + idx];
  }
  __syncthreads();
  const int e = e0 + (threadIdx.x & 63);
  const int j4 = threadIdx.x >> 6;
  float s[16];
#pragma unroll
  for (int jj = 0; jj < 16; jj++) s[jj] = 0.f;
  for (int i = 0; i < 64; i++) {
    float wv_ = Wp[(size_t)(h * 64 + i) * 512 + e];
#pragma unroll
    for (int jj = 0; jj < 16; jj++) s[jj] += As[i][j4 * 16 + jj] * wv_;
  }
#pragma unroll
  for (int jj = 0; jj < 16; jj++)
    W2T[(size_t)e * 512 + h * 64 + j4 * 16 + jj] = f2bf(s[jj]);
}

// ---------------- SAR branch ----------------
__global__ void k_conv3(const float* __restrict__ sar, const float* __restrict__ w3,
                        const float* __restrict__ b3, float* __restrict__ a)
{
  const int oc = blockIdx.y;
  const int p = blockIdx.x * 256 + threadIdx.x;
  const int y = p >> 8, x = p & 255;
  float s = b3[oc];
#pragma unroll
  for (int ic = 0; ic < 2; ic++) {
    const float* img = sar + ic * 65536;
    const float* w = w3 + oc * 18 + ic * 9;
#pragma unroll
    for (int k = 0; k < 9; k++) {
      int yy = y + k / 3 - 1, xx = x + k % 3 - 1;
      if ((unsigned)yy < 256u && (unsigned)xx < 256u) s += w[k] * img[yy * 256 + xx];
    }
  }
  a[oc * 65536 + p] = s;
}

__global__ void k_bnstats(const float* __restrict__ a, const float* __restrict__ g,
                          const float* __restrict__ b, float* __restrict__ bnp)
{
  const int ch = blockIdx.x;
  const int tid = threadIdx.x;
  const float* src = a + ch * 65536;
  float s = 0.f, sq = 0.f;
  for (int i = tid; i < 65536; i += 256) { float v = src[i]; s += v; sq += v * v; }
  __shared__ float rs[256], rq[256];
  rs[tid] = s; rq[tid] = sq;
  __syncthreads();
  for (int o = 128; o > 0; o >>= 1) {
    if (tid < o) { rs[tid] += rs[tid + o]; rq[tid] += rq[tid + o]; }
    __syncthreads();
  }
  if (tid == 0) {
    float mu = rs[0] * (1.f / 65536.f);
    float var = rq[0] * (1.f / 65536.f) - mu * mu;
    float scale = g[ch] / sqrtf(var + 1e-5f);
    bnp[ch] = scale;
    bnp[2 + ch] = b[ch] - mu * scale;
  }
}

__global__ void k_sar2(const float* __restrict__ a, const float* __restrict__ bnp,
                       const float* __restrict__ sb, float* __restrict__ ss)
{
  const int p = blockIdx.x * 256 + threadIdx.x;
  const int y = p >> 8, x = p & 255;
  const float sc0 = bnp[0], sc1 = bnp[1], sh0 = bnp[2], sh1 = bnp[3];
  float bs[9];
  float bn0c = 0.f, bn1c = 0.f;
#pragma unroll
  for (int k = 0; k < 9; k++) {
    int yy = y + k / 3 - 1, xx = x + k % 3 - 1;
    float v0 = 0.f, v1 = 0.f;
    if ((unsigned)yy < 256u && (unsigned)xx < 256u) {
      int q = yy * 256 + xx;
      v0 = a[q] * sc0 + sh0;
      v1 = a[65536 + q] * sc1 + sh1;
    }
    bs[k] = v0 + v1;
    if (k == 4) { bn0c = v0; bn1c = v1; }
  }
  float gv = (bs[6] + 2.f * bs[7] + bs[8]) - (bs[0] + 2.f * bs[1] + bs[2]);
  float gh = (bs[2] + 2.f * bs[5] + bs[8]) - (bs[0] + 2.f * bs[3] + bs[6]);
  float s0 = gv + sb[0], s1 = gh + sb[1], s2 = gv + sb[2], s3 = gh + sb[3];
  ss[p]         = sqrtf(s0 * s0 + s1 * s1) + bn0c;
  ss[65536 + p] = sqrtf(s2 * s2 + s3 * s3) + bn1c;
}

// =====================================================================
// Mask via MFMA GEMM. mask = L1 + beta_c*(W(p)-wsum_c) + sigmoid(L2),
// L1/L2 linear in the 50-value patch; K=192 hi/lo-compensated bf16 GEMM.
// Epilogue stages mask (f32) through LDS so the VB gate is done with
// coalesced ushort8 RMW (16B/lane) instead of scalar u16 RMW.
// =====================================================================

// ---- k_dwprep: build BM [1024][192] bf16 and border tables TB [512][32] ----
__global__ void k_dwprep(const float* __restrict__ dw, const float* __restrict__ db,
                         const float* __restrict__ w2, const float* __restrict__ b2,
                         const float* __restrict__ w32, const float* __restrict__ b32,
                         u16* __restrict__ BM, float* __restrict__ TB)
{
  const int c = blockIdx.x * 256 + threadIdx.x;
  if (c >= 512) return;
  float d[25];
  float wsum = 0.f;
#pragma unroll
  for (int t = 0; t < 25; t++) { d[t] = dw[c * 25 + t]; wsum += d[t]; }
  const float a = w2[2 * c], b = w2[2 * c + 1], beta = b2[c];
  const float C1 = beta * (1.f + wsum) + db[c];

  u16* rL1 = BM + (size_t)((c >> 6) * 128 + (c & 63)) * 192;
  u16* rL2 = rL1 + (size_t)64 * 192;

#pragma unroll
  for (int k = 0; k < 64; k++) {
    float v1;
    if (k < 25)       v1 = a * (d[k] + (k == 12 ? 1.f : 0.f));
    else if (k < 50)  v1 = b * (d[k - 25] + (k == 37 ? 1.f : 0.f));
    else if (k == 63) v1 = C1;
    else              v1 = 0.f;
    u16 h = f2bf(v1); u16 l = f2bf(v1 - bf2f(h));
    rL1[k] = h; rL1[64 + k] = h; rL1[128 + k] = l;
  }
#pragma unroll
  for (int k = 0; k < 64; k++) {
    float v2 = 0.f;
    if (k < 50) {
      const int t = (k < 25) ? k : (k - 25);
      const int dy = t / 5 - 2, dx = t % 5 - 2;
      if (dy >= -1 && dy <= 1 && dx >= -1 && dx <= 1)
        v2 = w32[c * 18 + ((k < 25) ? 0 : 9) + (dy + 1) * 3 + (dx + 1)];
    }
    if (k == 63) v2 = b32[c];
    u16 h = f2bf(v2); u16 l = f2bf(v2 - bf2f(h));
    rL2[k] = h; rL2[64 + k] = h; rL2[128 + k] = l;
  }

  // border tables: W = wsum - T[mt] - B[mb] - L[ml] - R[mr] + corners
  float rs[5], cs[5];
#pragma unroll
  for (int i = 0; i < 5; i++) {
    rs[i] = d[i*5] + d[i*5+1] + d[i*5+2] + d[i*5+3] + d[i*5+4];
    cs[i] = d[i] + d[5+i] + d[10+i] + d[15+i] + d[20+i];
  }
  float* tb = TB + (size_t)c * 32;
  tb[0] = rs[0];  tb[1] = rs[0] + rs[1];          // T1, T2 (missing top rows)
  tb[2] = rs[4];  tb[3] = rs[3] + rs[4];          // B1, B2
  tb[4] = cs[0];  tb[5] = cs[0] + cs[1];          // L1, L2
  tb[6] = cs[4];  tb[7] = cs[3] + cs[4];          // R1, R2
  tb[8]  = d[0];           tb[9]  = d[0] + d[1];            // TL(1,1) TL(1,2)
  tb[10] = d[0] + d[5];    tb[11] = d[0] + d[1] + d[5] + d[6];
  tb[12] = d[4];           tb[13] = d[3] + d[4];            // TR
  tb[14] = d[4] + d[9];    tb[15] = d[3] + d[4] + d[8] + d[9];
  tb[16] = d[20];          tb[17] = d[20] + d[21];          // BL
  tb[18] = d[15] + d[20];  tb[19] = d[15] + d[16] + d[20] + d[21];
  tb[20] = d[24];          tb[21] = d[23] + d[24];          // BR
  tb[22] = d[19] + d[24];  tb[23] = d[18] + d[19] + d[23] + d[24];
#pragma unroll
  for (int i = 24; i < 32; i++) tb[i] = 0.f;
}

// ---- k_patch: build P [65536][192] bf16 patch matrix from SS ----
__global__ __launch_bounds__(256) void k_patch(const float* __restrict__ ss, u16* __restrict__ P)
{
  __shared__ float s0r[5][264];
  __shared__ float s1r[5][264];
  const int y = blockIdx.x;       // one image row per block
  const int tid = threadIdx.x;
  for (int i = tid; i < 1300; i += 256) {
    const int r = i / 260, col = i - r * 260;
    const int yy = y + r - 2, xx = col - 2;
    const bool in = ((unsigned)yy < 256u) & ((unsigned)xx < 256u);
    const int gp = yy * 256 + xx;
    s0r[r][col] = in ? ss[gp] : 0.f;
    s1r[r][col] = in ? ss[65536 + gp] : 0.f;
  }
  __syncthreads();
  const int x = tid;
  unsigned arr32[64];              // k[0..127]; k[128..191] is a copy of k[0..63]
#pragma unroll
  for (int i = 0; i < 64; i++) arr32[i] = 0u;
#define PUTK(k, v) arr32[(k) >> 1] |= ((unsigned)(v)) << (((k) & 1) * 16)
#pragma unroll
  for (int dy = 0; dy < 5; dy++)
#pragma unroll
    for (int dx = 0; dx < 5; dx++) {
      const int t = dy * 5 + dx;
      const float v0 = s0r[dy][x + dx];
      const float v1 = s1r[dy][x + dx];
      const u16 h0 = f2bf(v0); const u16 l0 = f2bf(v0 - bf2f(h0));
      const u16 h1 = f2bf(v1); const u16 l1 = f2bf(v1 - bf2f(h1));
      PUTK(t, h0);      PUTK(25 + t, h1);
      PUTK(64 + t, l0); PUTK(89 + t, l1);
    }
  PUTK(63, 0x3F80u);               // 1.0 for bias slot (block2 copy gives k191=1.0)
#undef PUTK
  unsigned* dst = (unsigned*)(P + (size_t)(y * 256 + x) * 192);
#pragma unroll
  for (int i = 0; i < 16; i++)
    *(uint4*)(dst + i * 4) = *(const uint4*)(arr32 + i * 4);
#pragma unroll
  for (int i = 0; i < 8; i++)
    *(uint4*)(dst + 64 + i * 4) = *(const uint4*)(arr32 + i * 4);
}

// ---- k_maskmm: C = P @ BM^T fused with sigmoid/border/V-gate, in-place VB ----
// Tile: M=128 px, N=128 (64 ch: n<64 -> L1, n>=64 -> L2), K=192 (no outer loop).
// 4 waves stacked in M (wave tile 32x128) so each lane holds L1 and L2 of the
// SAME channel. Mask staged f32 in LDS; VB gated with coalesced ushort8 RMW.
__global__ __launch_bounds__(256) void k_maskmm(
    const u16* __restrict__ P, const u16* __restrict__ BM,
    const float* __restrict__ TB, const float* __restrict__ beta_p,
    u16* __restrict__ VB)
{
  // pool: staging (16 KiB) aliased over mask tile [128][68] f32 (34 KiB)
  __shared__ __align__(16) float lds_pool[128 * 68];
  uint4* smem = (uint4*)lds_pool;
  const int tid  = threadIdx.x;
  const int lane = tid & 63;
  const int wv   = tid >> 6;
  const int m0   = blockIdx.x * 128;
  const int g    = blockIdx.y;          // channel group (64 ch)

  const int q0 = tid, q1 = tid + 256;
  const size_t arow0 = (size_t)(m0 + (q0 >> 2)) * 192 + (q0 & 3) * 8;
  const size_t arow1 = (size_t)(m0 + (q1 >> 2)) * 192 + (q1 & 3) * 8;
  const size_t brow0 = (size_t)(g * 128 + (q0 >> 2)) * 192 + (q0 & 3) * 8;
  const size_t brow1 = (size_t)(g * 128 + (q1 >> 2)) * 192 + (q1 & 3) * 8;

  f32x4 acc[2][8] = {};
  const char* lAc = (const char*)smem;
  const char* lBc = (const char*)(smem + 512);
  const int ko = (lane >> 4) * 16;
  const int ma = lane & 15;

  for (int k0 = 0; k0 < 192; k0 += 32) {
    __syncthreads();
    GLOAD_LDS16(&P[arow0 + k0],  &smem[q0]);
    GLOAD_LDS16(&P[arow1 + k0],  &smem[q1]);
    GLOAD_LDS16(&BM[brow0 + k0], &smem[512 + q0]);
    GLOAD_LDS16(&BM[brow1 + k0], &smem[512 + q1]);
    __syncthreads();
    short8 af[2], bfr[8];
#pragma unroll
    for (int mt = 0; mt < 2; mt++)
      af[mt] = *(const short8*)(lAc + (wv * 32 + mt * 16 + ma) * 64 + ko);
#pragma unroll
    for (int nt = 0; nt < 8; nt++)
      bfr[nt] = *(const short8*)(lBc + (nt * 16 + ma) * 64 + ko);
#pragma unroll
    for (int mt = 0; mt < 2; mt++)
#pragma unroll
      for (int nt = 0; nt < 8; nt++)
        acc[mt][nt] = __builtin_amdgcn_mfma_f32_16x16x32_bf16(af[mt], bfr[nt], acc[mt][nt], 0, 0, 0);
  }

  __syncthreads();     // all waves done with staging reads; pool reused as mask tile
  const int col = lane & 15, rq = (lane >> 4) * 4;
  const int y   = m0 >> 8;                       // block covers half a row: y uniform
  const int mty = (y < 2) ? (2 - y) : 0;
  const int mby = (y > 253) ? (y - 253) : 0;
#pragma unroll
  for (int mt = 0; mt < 2; mt++) {
#pragma unroll
    for (int nt = 0; nt < 4; nt++) {
      const int ch = g * 64 + nt * 16 + col;
#pragma unroll
      for (int r = 0; r < 4; r++) {
        const int pxl = wv * 32 + mt * 16 + rq + r;      // 0..127
        const float L1 = acc[mt][nt][r];
        const float L2 = acc[mt][nt + 4][r];
        const int x  = (m0 + pxl) & 255;
        const int ml = (x < 2) ? (2 - x) : 0;
        const int mr = (x > 253) ? (x - 253) : 0;
        float wc = 0.f;
        if (mty | mby | ml | mr) {
          const float* tb = &TB[(size_t)ch * 32];
          float W = 0.f;
          if (mty) W -= tb[mty - 1];
          if (mby) W -= tb[2 + mby - 1];
          if (ml)  W -= tb[4 + ml - 1];
          if (mr)  W -= tb[6 + mr - 1];
          if (mty && ml) W += tb[8  + (mty - 1) * 2 + (ml - 1)];
          if (mty && mr) W += tb[12 + (mty - 1) * 2 + (mr - 1)];
          if (mby && ml) W += tb[16 + (mby - 1) * 2 + (ml - 1)];
          if (mby && mr) W += tb[20 + (mby - 1) * 2 + (mr - 1)];
          wc = beta_p[ch] * W;
        }
        const float sig = 1.f / (1.f + __expf(-L2));
        lds_pool[pxl * 68 + nt * 16 + col] = L1 + wc + sig;
      }
    }
  }
  __syncthreads();
  // coalesced gate: 4 chunks/thread, chunk = 8 ch (16 B) of one pixel row
#pragma unroll
  for (int k = 0; k < 4; k++) {
    const int cid = k * 256 + tid;
    const int pxl = cid >> 3;              // 0..127
    const int cp  = (cid & 7) * 8;         // 0..56
    const float4 ma0 = *(const float4*)&lds_pool[pxl * 68 + cp];
    const float4 ma1 = *(const float4*)&lds_pool[pxl * 68 + cp + 4];
    u16* vp = &VB[(size_t)(m0 + pxl) * 512 + g * 64 + cp];
    short8 vv = *(const short8*)vp;
    short8 o;
    o[0] = (short)f2bf(bf2f((u16)vv[0]) * ma0.x);
    o[1] = (short)f2bf(bf2f((u16)vv[1]) * ma0.y);
    o[2] = (short)f2bf(bf2f((u16)vv[2]) * ma0.z);
    o[3] = (short)f2bf(bf2f((u16)vv[3]) * ma0.w);
    o[4] = (short)f2bf(bf2f((u16)vv[4]) * ma1.x);
    o[5] = (short)f2bf(bf2f((u16)vv[5]) * ma1.y);
    o[6] = (short)f2bf(bf2f((u16)vv[6]) * ma1.z);
    o[7] = (short)f2bf(bf2f((u16)vv[7]) * ma1.w);
    *(short8*)vp = o;
  }
}

// =====================================================================
// Vectorized depthwise 3x3 (plane layout). Wave = 16 x-subgroups x 4 channels;
// lane loads ushort4 per row, halo via shfl; edge subgroups do predicated u16 load.
// =====================================================================
DEVFN void dw3x3_row4(const u16* plane, int y, int x0, int sub,
                      const float* w9, float& s0, float& s1, float& s2, float& s3)
{
#pragma unroll
  for (int r = 0; r < 3; r++) {
    int yy = y + r - 1;
    if ((unsigned)yy < 256u) {       // block-uniform branch
      const int base = yy * 256 + x0 + sub * 4;
      ushort4 p = *(const ushort4*)&plane[base];
      float v0 = bf2f(p.x), v1 = bf2f(p.y), v2 = bf2f(p.z), v3 = bf2f(p.w);
      float lf = __shfl_up(v3, 1);
      float rt = __shfl_down(v0, 1);
      if (sub == 0)  lf = (x0 > 0)   ? bf2f(plane[yy * 256 + x0 - 1])  : 0.f;
      if (sub == 15) rt = (x0 < 192) ? bf2f(plane[yy * 256 + x0 + 64]) : 0.f;
      const float wa = w9[r * 3], wb = w9[r * 3 + 1], wc = w9[r * 3 + 2];
      s0 += wa * lf + wb * v0 + wc * v1;
      s1 += wa * v0 + wb * v1 + wc * v2;
      s2 += wa * v1 + wb * v2 + wc * v3;
      s3 += wa * v2 + wb * v3 + wc * rt;
    }
  }
}

// pe1: dconv3x3(VT) -> exact GELU -> GT (plane layout, vectorized)
__global__ __launch_bounds__(256) void k_pe1v(const u16* __restrict__ vt,
    const float* __restrict__ w, u16* __restrict__ gt)
{
  const int t = blockIdx.x;
  const int y = t >> 2, x0 = (t & 3) * 64;
  const int cg = blockIdx.y * 64;
  const int lane = threadIdx.x & 63, wvq = threadIdx.x >> 6;
  const int sub = lane & 15, chq = lane >> 4;
#pragma unroll
  for (int i = 0; i < 4; i++) {
    const int c = cg + wvq * 16 + i * 4 + chq;
    const u16* plane = vt + (size_t)c * 65536;
    float w9[9];
#pragma unroll
    for (int k = 0; k < 9; k++) w9[k] = w[c * 9 + k];
    float s0 = 0.f, s1 = 0.f, s2 = 0.f, s3 = 0.f;
    dw3x3_row4(plane, y, x0, sub, w9, s0, s1, s2, s3);
    const float ksc = 0.70710678118654752f;
    s0 = 0.5f * s0 * (1.f + erff(s0 * ksc));
    s1 = 0.5f * s1 * (1.f + erff(s1 * ksc));
    s2 = 0.5f * s2 * (1.f + erff(s2 * ksc));
    s3 = 0.5f * s3 * (1.f + erff(s3 * ksc));
    ushort4 o; o.x = f2bf(s0); o.y = f2bf(s1); o.z = f2bf(s2); o.w = f2bf(s3);
    *(ushort4*)&gt[(size_t)c * 65536 + y * 256 + x0 + sub * 4] = o;
  }
}

// pe2: dconv3x3(GT), LDS transpose, coalesced bf16 write to PEB [n][c].
// (PE is added to out inside the final GEMM epilogue — no fp32 RMW.)
__global__ __launch_bounds__(256) void k_pe2v(const u16* __restrict__ gt,
    const float* __restrict__ w, u16* __restrict__ peb)
{
  __shared__ float tile[64][65];
  const int t = blockIdx.x;
  const int y = t >> 2, x0 = (t & 3) * 64;
  const int cg = blockIdx.y * 64;
  const int lane = threadIdx.x & 63, wvq = threadIdx.x >> 6;
  const int sub = lane & 15, chq = lane >> 4;
#pragma unroll
  for (int i = 0; i < 4; i++) {
    const int cl = wvq * 16 + i * 4 + chq;
    const int c = cg + cl;
    const u16* plane = gt + (size_t)c * 65536;
    float w9[9];
#pragma unroll
    for (int k = 0; k < 9; k++) w9[k] = w[c * 9 + k];
    float s0 = 0.f, s1 = 0.f, s2 = 0.f, s3 = 0.f;
    dw3x3_row4(plane, y, x0, sub, w9, s0, s1, s2, s3);
    tile[cl][sub * 4 + 0] = s0;
    tile[cl][sub * 4 + 1] = s1;
    tile[cl][sub * 4 + 2] = s2;
    tile[cl][sub * 4 + 3] = s3;
  }
  __syncthreads();
  // 64 px x 64 ch = 512 ushort8 chunks; 2 per thread, fully coalesced 16B/lane
#pragma unroll
  for (int k = 0; k < 2; k++) {
    const int cid = k * 256 + threadIdx.x;
    const int q = cid & 7, pl = cid >> 3;          // q: 8-ch group, pl: pixel 0..63
    short8 o;
#pragma unroll
    for (int j = 0; j < 8; j++) o[j] = (short)f2bf(tile[q * 8 + j][pl]);
    *(short8*)&peb[(size_t)(y * 256 + x0 + pl) * 512 + cg + q * 8] = o;
  }
}

// =====================================================================
extern "C" void kernel_launch(void* const* d_in, const int* in_sizes, int n_in,
                              void* d_out, int out_size, void* d_ws, size_t ws_size,
                              hipStream_t stream)
{
  (void)in_sizes; (void)n_in; (void)out_size;
  const float* x    = (const float*)d_in[0];
  const float* sar  = (const float*)d_in[1];
  const float* Wq   = (const float*)d_in[2];
  const float* Wk   = (const float*)d_in[3];
  const float* Wv   = (const float*)d_in[4];
  const float* resc = (const float*)d_in[5];
  const float* Wp   = (const float*)d_in[6];
  const float* bp   = (const float*)d_in[7];
  const float* pe1w = (const float*)d_in[8];
  const float* pe2w = (const float*)d_in[9];
  const float* w3   = (const float*)d_in[10];
  const float* b3   = (const float*)d_in[11];
  const float* bng  = (const float*)d_in[12];
  const float* bnb  = (const float*)d_in[13];
  const float* sb   = (const float*)d_in[14];
  const float* w2c  = (const float*)d_in[15];
  const float* b2c  = (const float*)d_in[16];
  const float* w32  = (const float*)d_in[17];
  const float* b32  = (const float*)d_in[18];
  const float* dw   = (const float*)d_in[19];
  const float* db   = (const float*)d_in[20];
  float* out = (float*)d_out;

  if (ws_size < WS_NEEDED)
    fprintf(stderr, "MS_MSA: workspace too small: have %zu need %zu\n", ws_size, WS_NEEDED);

  char* ws = (char*)d_ws;
  u16* XB    = (u16*)(ws + OFF_XB);
  u16* XBT   = (u16*)(ws + OFF_XBT);
  u16* VB    = (u16*)(ws + OFF_VB);
  u16* VT    = (u16*)(ws + OFF_VT);
  float* GPART = (float*)(ws + OFF_GPART);
  float* G     = (float*)(ws + OFF_G);
  float* TQ    = (float*)(ws + OFF_TQ);
  float* TK    = (float*)(ws + OFF_TK);
  u16* WVT   = (u16*)(ws + OFF_WVT);
  u16* W2T   = (u16*)(ws + OFF_W2T);
  float* ASAR = (float*)(ws + OFF_ASAR);
  float* SS   = (float*)(ws + OFF_SS);
  float* BNP  = (float*)(ws + OFF_BNP);
  float* QN   = (float*)(ws + OFF_QN);
  float* KN   = (float*)(ws + OFF_KN);
  float* ATTN = (float*)(ws + OFF_ATTN);
  u16*  BM   = (u16*)(ws + OFF_BM);
  float* TBt  = (float*)(ws + OFF_TB);
  u16* GT  = XBT;                 // alias: XBT dead after Gram
  u16* P   = (u16*)(ws + OFF_GPART);  // alias: GPART dead after k_reduce_g
  u16* PEB = XB;                  // alias: XB dead after gemm_bt<0>

  // --- x -> bf16 (row + transposed) ---
  k_cast_transpose<<<dim3(1024, 8), 256, 0, stream>>>(x, XB, XBT);
  // --- G = X^T X ---
  gemm_bt<1><<<dim3(4, 4, GSPLIT), 256, 0, stream>>>(XBT, NTOK, XBT, NTOK, GKLEN, GPART, nullptr, nullptr);
  k_reduce_g<<<1024, 256, 0, stream>>>(GPART, G);
  // --- v_inp = x @ Wv ---
  k_transpose_w<<<dim3(8, 8), 256, 0, stream>>>(Wv, WVT);
  gemm_bt<0><<<dim3(512, 4), 256, 0, stream>>>(XB, 512, WVT, 512, 512, VB, nullptr, nullptr);
  k_tbf16<<<dim3(1024, 8), 256, 0, stream>>>(VB, VT, 65536, 512);   // VT = ungated v^T for pe1
  // --- attention stats ---
  k_gw<<<dim3(8, 8, 2), 256, 0, stream>>>(G, Wq, Wk, TQ, TK);
  k_norms<<<256, 256, 0, stream>>>(Wq, TQ, Wk, TK, QN, KN);
  k_attn<<<8, 256, 0, stream>>>(Wk, TQ, QN, KN, resc, ATTN);
  k_w2t<<<64, 256, 0, stream>>>(ATTN, Wp, W2T);
  // --- SAR branch ---
  k_conv3<<<dim3(256, 2), 256, 0, stream>>>(sar, w3, b3, ASAR);
  k_bnstats<<<2, 256, 0, stream>>>(ASAR, bng, bnb, BNP);
  k_sar2<<<256, 256, 0, stream>>>(ASAR, BNP, sb, SS);
  // --- mask via compensated bf16 MFMA GEMM, gate V in-place ([n][c]) ---
  k_dwprep<<<2, 256, 0, stream>>>(dw, db, w2c, b2c, w32, b32, BM, TBt);
  k_patch<<<256, 256, 0, stream>>>(SS, P);
  k_maskmm<<<dim3(512, 8), 256, 0, stream>>>(P, BM, TBt, b2c, VB);
  // --- positional branch -> PEB bf16 [n][c] (XB alias) ---
  k_pe1v<<<dim3(1024, 8), 256, 0, stream>>>(VT, pe1w, GT);
  k_pe2v<<<dim3(1024, 8), 256, 0, stream>>>(GT, pe2w, PEB);
  // --- out = (v*mask) @ W2 + bp + PE  (single writer of out) ---
  gemm_bt<3><<<dim3(512, 4), 256, 0, stream>>>(VB, 512, W2T, 512, 512, out, bp, PEB);
}

// Round 5
// 890.939 us; speedup vs baseline: 1.0970x; 1.0225x over previous
//
#include <hip/hip_runtime.h>
#include <cstdint>
#include <cstdio>

typedef unsigned short u16;
typedef __attribute__((ext_vector_type(8))) short short8;   // 8 bf16 (4 VGPRs)
typedef __attribute__((ext_vector_type(4))) float f32x4;

#define DEVFN __device__ __forceinline__

DEVFN u16 f2bf(float f){ union{float f; unsigned u;} v; v.f=f; unsigned r = v.u + 0x7fffu + ((v.u>>16)&1u); return (u16)(r>>16); }
DEVFN float bf2f(u16 h){ union{unsigned u; float f;} v; v.u = ((unsigned)h)<<16; return v.f; }

// async global->LDS, 16B per lane (dwordx4). LDS dest must be wave-uniform base + lane*16.
#define GLOAD_LDS16(gp, lp) __builtin_amdgcn_global_load_lds( \
    (const __attribute__((address_space(1))) void*)(gp), \
    (__attribute__((address_space(3))) void*)(lp), 16, 0, 0)

// ---------------- problem constants ----------------
static constexpr int NTOK = 65536;   // H*W
static constexpr int GSPLIT = 32;    // split-K slabs for Gram
static constexpr int GKLEN  = NTOK / GSPLIT;

// ---------------- workspace layout (bytes) ----------------
static constexpr size_t MB = 1024 * 1024;
static constexpr size_t OFF_XB    = 0;          // bf16 x  [n][c]    64 MiB   (alias: PEB after gemm_v)
static constexpr size_t OFF_XBT   = 64 * MB;    // bf16 x^T [c][n]   64 MiB   (alias: GT)
static constexpr size_t OFF_VB    = 128 * MB;   // bf16 v_inp [n][c] 64 MiB   (gated in-place by k_maskmm)
static constexpr size_t OFF_VT    = 192 * MB;   // bf16 v^T [c][n]   64 MiB
static constexpr size_t OFF_GPART = 256 * MB;   // fp32 [32][512][512] 32 MiB (alias: P patch matrix 25.2 MiB)
static constexpr size_t OFF_G     = 288 * MB;
static constexpr size_t OFF_TQ    = 289 * MB;
static constexpr size_t OFF_TK    = 290 * MB;
static constexpr size_t OFF_WVT   = 291 * MB;            // bf16 Wv^T
static constexpr size_t OFF_W2T   = 291 * MB + 524288;   // bf16 W2^T
static constexpr size_t OFF_ASAR  = 292 * MB;            // fp32 [2][65536]
static constexpr size_t OFF_SS    = 292 * MB + 524288;   // fp32 [2][65536]
static constexpr size_t OFF_BNP   = 293 * MB;
static constexpr size_t OFF_QN    = 293 * MB + 4096;
static constexpr size_t OFF_KN    = 293 * MB + 8192;
static constexpr size_t OFF_ATTN  = 293 * MB + 12288;    // fp32 [8][64][64] = 128 KiB
static constexpr size_t OFF_BM    = 293 * MB + 262144;   // bf16 [1024][192] mask-GEMM weights (384 KiB)
static constexpr size_t OFF_TB    = 293 * MB + 786432;   // fp32 [512][32] border tables (64 KiB)
static constexpr size_t WS_NEEDED = 294 * MB;

// =====================================================================
// bf16 MFMA GEMM: C[M][512] = A[M][K] * B with B stored as [N][K] (B^T).
// 128x128 tile, 4 waves 2x2, wave = 64x64 via 4x4 16x16x32 frags.
// 2-phase double-buffered staging (T3-min): issue next tile's
// global_load_lds BEFORE ds_read+MFMA of the current tile; one barrier
// per K-step (its implicit vmcnt(0) lands after MFMA covers load latency).
// MODE 0: bf16 C. MODE 1: fp32 partial slab (split-K, z).
// MODE 3: fp32 C + bias + bf16 PE add (final output, single writer of out).
// =====================================================================
template<int MODE>
__global__ __launch_bounds__(256) void gemm_bt(
    const u16* __restrict__ A, int lda,
    const u16* __restrict__ B, int ldb,
    int klen,
    void* __restrict__ Cout,
    const float* __restrict__ bias,
    const u16* __restrict__ pe)
{
  __shared__ uint4 smem[2048];  // 2 buffers x (A 128x32 [512] + B 128x32 [512])
  const int tid  = threadIdx.x;
  const int lane = tid & 63;
  const int wv   = tid >> 6;
  const int wm   = (wv >> 1) * 64;
  const int wn   = (wv & 1) * 64;
  const int m0   = blockIdx.x * 128;
  const int n0   = blockIdx.y * 128;
  const int kb   = blockIdx.z * klen;

  const int q0 = tid, q1 = tid + 256;
  const size_t arow0 = (size_t)(m0 + (q0 >> 2)) * lda + (q0 & 3) * 8;
  const size_t arow1 = (size_t)(m0 + (q1 >> 2)) * lda + (q1 & 3) * 8;
  const size_t brow0 = (size_t)(n0 + (q0 >> 2)) * ldb + (q0 & 3) * 8;
  const size_t brow1 = (size_t)(n0 + (q1 >> 2)) * ldb + (q1 & 3) * 8;

  f32x4 acc[4][4] = {};
  const int ko = (lane >> 4) * 16;
  const int ma = lane & 15;
  const int NT = klen >> 5;

  // prologue: stage tile 0 into buf 0
  GLOAD_LDS16(&A[arow0 + kb], &smem[q0]);
  GLOAD_LDS16(&A[arow1 + kb], &smem[q1]);
  GLOAD_LDS16(&B[brow0 + kb], &smem[512 + q0]);
  GLOAD_LDS16(&B[brow1 + kb], &smem[512 + q1]);
  __syncthreads();                      // drains vmcnt -> tile 0 visible

  int cur = 0;
  for (int t = 0; t < NT; ++t) {
    // issue next tile's loads into the other buffer (overlaps with compute)
    if (t + 1 < NT) {
      const int kn = kb + (t + 1) * 32;
      uint4* nb = &smem[(cur ^ 1) * 1024];
      GLOAD_LDS16(&A[arow0 + kn], &nb[q0]);
      GLOAD_LDS16(&A[arow1 + kn], &nb[q1]);
      GLOAD_LDS16(&B[brow0 + kn], &nb[512 + q0]);
      GLOAD_LDS16(&B[brow1 + kn], &nb[512 + q1]);
    }
    const char* lAc = (const char*)&smem[cur * 1024];
    const char* lBc = (const char*)&smem[cur * 1024 + 512];
    short8 af[4], bfr[4];
#pragma unroll
    for (int mt = 0; mt < 4; mt++)
      af[mt] = *(const short8*)(lAc + (wm + mt * 16 + ma) * 64 + ko);
#pragma unroll
    for (int nt = 0; nt < 4; nt++)
      bfr[nt] = *(const short8*)(lBc + (wn + nt * 16 + ma) * 64 + ko);
#pragma unroll
    for (int mt = 0; mt < 4; mt++)
#pragma unroll
      for (int nt = 0; nt < 4; nt++)
        acc[mt][nt] = __builtin_amdgcn_mfma_f32_16x16x32_bf16(af[mt], bfr[nt], acc[mt][nt], 0, 0, 0);
    __syncthreads();   // drains vmcnt(0)+lgkmcnt(0): next tile visible, reads of cur done
    cur ^= 1;
  }

  const int col = lane & 15;
  const int rq  = (lane >> 4) * 4;
  float* Cf = (float*)Cout;
  u16*   Ch = (u16*)Cout;
  if (MODE == 1) Cf += (size_t)blockIdx.z * 512 * 512;
#pragma unroll
  for (int mt = 0; mt < 4; mt++) {
#pragma unroll
    for (int nt = 0; nt < 4; nt++) {
      const int mbase = m0 + wm + mt * 16 + rq;
      const int nn    = n0 + wn + nt * 16 + col;
#pragma unroll
      for (int r = 0; r < 4; r++) {
        float vv = acc[mt][nt][r];
        size_t idx = (size_t)(mbase + r) * 512 + nn;
        if (MODE == 0)      Ch[idx] = f2bf(vv);
        else if (MODE == 1) Cf[idx] = vv;
        else                Cf[idx] = vv + bias[nn] + bf2f(pe[idx]);
      }
    }
  }
}

// ---------------- x fp32 [n][512] -> bf16 xb [n][512] and xbT [512][n] ----------------
__global__ void k_cast_transpose(const float* __restrict__ x, u16* __restrict__ xb, u16* __restrict__ xbT)
{
  __shared__ u16 tile[64][72];
  const int t0 = blockIdx.x * 64, c0 = blockIdx.y * 64;
  const int tx = threadIdx.x & 15, ty = threadIdx.x >> 4;
#pragma unroll
  for (int p = 0; p < 4; p++) {
    int t = ty + p * 16;
    float4 v = *(const float4*)&x[(size_t)(t0 + t) * 512 + c0 + tx * 4];
    ushort4 u; u.x = f2bf(v.x); u.y = f2bf(v.y); u.z = f2bf(v.z); u.w = f2bf(v.w);
    *(ushort4*)&xb[(size_t)(t0 + t) * 512 + c0 + tx * 4] = u;
    tile[t][tx*4+0] = u.x; tile[t][tx*4+1] = u.y; tile[t][tx*4+2] = u.z; tile[t][tx*4+3] = u.w;
  }
  __syncthreads();
#pragma unroll
  for (int p = 0; p < 4; p++) {
    int c = ty + p * 16;
    ushort4 u;
    u.x = tile[tx*4+0][c]; u.y = tile[tx*4+1][c]; u.z = tile[tx*4+2][c]; u.w = tile[tx*4+3][c];
    *(ushort4*)&xbT[(size_t)(c0 + c) * 65536 + t0 + tx * 4] = u;
  }
}

// ---------------- generic bf16 tiled transpose: src[srows][scols] -> dst[scols][srows] ----------------
__global__ void k_tbf16(const u16* __restrict__ src, u16* __restrict__ dst, int srows, int scols)
{
  __shared__ u16 tile[64][72];
  const int r0 = blockIdx.x * 64, c0v = blockIdx.y * 64;
  const int tx = threadIdx.x & 15, ty = threadIdx.x >> 4;
#pragma unroll
  for (int p = 0; p < 4; p++) {
    int r = ty + p * 16;
    ushort4 u = *(const ushort4*)&src[(size_t)(r0 + r) * scols + c0v + tx * 4];
    tile[r][tx*4+0] = u.x; tile[r][tx*4+1] = u.y; tile[r][tx*4+2] = u.z; tile[r][tx*4+3] = u.w;
  }
  __syncthreads();
#pragma unroll
  for (int p = 0; p < 4; p++) {
    int c = ty + p * 16;
    ushort4 u;
    u.x = tile[tx*4+0][c]; u.y = tile[tx*4+1][c]; u.z = tile[tx*4+2][c]; u.w = tile[tx*4+3][c];
    *(ushort4*)&dst[(size_t)(c0v + c) * srows + r0 + tx * 4] = u;
  }
}

// ---------------- W fp32 [512][512] -> bf16 W^T ----------------
__global__ void k_transpose_w(const float* __restrict__ Wsrc, u16* __restrict__ WT)
{
  __shared__ u16 tile[64][72];
  const int k0 = blockIdx.x * 64, n0 = blockIdx.y * 64;
  const int tx = threadIdx.x & 15, ty = threadIdx.x >> 4;
#pragma unroll
  for (int p = 0; p < 4; p++) {
    int t = ty + p * 16;
    float4 v = *(const float4*)&Wsrc[(size_t)(k0 + t) * 512 + n0 + tx * 4];
    tile[t][tx*4+0] = f2bf(v.x); tile[t][tx*4+1] = f2bf(v.y);
    tile[t][tx*4+2] = f2bf(v.z); tile[t][tx*4+3] = f2bf(v.w);
  }
  __syncthreads();
#pragma unroll
  for (int p = 0; p < 4; p++) {
    int c = ty + p * 16;
    ushort4 u;
    u.x = tile[tx*4+0][c]; u.y = tile[tx*4+1][c]; u.z = tile[tx*4+2][c]; u.w = tile[tx*4+3][c];
    *(ushort4*)&WT[(size_t)(n0 + c) * 512 + k0 + tx * 4] = u;
  }
}

// ---------------- reduce Gram partials ----------------
__global__ void k_reduce_g(const float* __restrict__ part, float* __restrict__ G)
{
  const int i = blockIdx.x * 256 + threadIdx.x;
  float s = 0.f;
  for (int z = 0; z < GSPLIT; z++) s += part[(size_t)z * 262144 + i];
  G[i] = s;
}

// ---------------- Tq = G@Wq, Tk = G@Wk ----------------
__global__ __launch_bounds__(256) void k_gw(const float* __restrict__ G,
    const float* __restrict__ Wq, const float* __restrict__ Wk,
    float* __restrict__ Tq, float* __restrict__ Tk)
{
  const float* Bm = blockIdx.z ? Wk : Wq;
  float* Cm = blockIdx.z ? Tk : Tq;
  __shared__ float As[64][68];
  __shared__ float Bs[64][68];
  const int i0 = blockIdx.x * 64, j0 = blockIdx.y * 64;
  const int tx = threadIdx.x & 15, ty = threadIdx.x >> 4;
  float acc[4][4] = {};
  for (int k0 = 0; k0 < 512; k0 += 64) {
    __syncthreads();
#pragma unroll
    for (int p = 0; p < 4; p++) {
      int r = ty + p * 16;
      float4 a = *(const float4*)&G [(size_t)(i0 + r) * 512 + k0 + tx * 4];
      float4 b = *(const float4*)&Bm[(size_t)(k0 + r) * 512 + j0 + tx * 4];
      *(float4*)&As[r][tx * 4] = a;
      *(float4*)&Bs[r][tx * 4] = b;
    }
    __syncthreads();
    for (int kk = 0; kk < 64; kk++) {
      float a0 = As[ty*4+0][kk], a1 = As[ty*4+1][kk], a2 = As[ty*4+2][kk], a3 = As[ty*4+3][kk];
      float4 bq = *(const float4*)&Bs[kk][tx * 4];
      acc[0][0] += a0*bq.x; acc[0][1] += a0*bq.y; acc[0][2] += a0*bq.z; acc[0][3] += a0*bq.w;
      acc[1][0] += a1*bq.x; acc[1][1] += a1*bq.y; acc[1][2] += a1*bq.z; acc[1][3] += a1*bq.w;
      acc[2][0] += a2*bq.x; acc[2][1] += a2*bq.y; acc[2][2] += a2*bq.z; acc[2][3] += a2*bq.w;
      acc[3][0] += a3*bq.x; acc[3][1] += a3*bq.y; acc[3][2] += a3*bq.z; acc[3][3] += a3*bq.w;
    }
  }
#pragma unroll
  for (int u = 0; u < 4; u++) {
    float4 o = make_float4(acc[u][0], acc[u][1], acc[u][2], acc[u][3]);
    *(float4*)&Cm[(size_t)(i0 + ty * 4 + u) * 512 + j0 + tx * 4] = o;
  }
}

// ---------------- norms ----------------
__global__ void k_norms(const float* __restrict__ Wq, const float* __restrict__ Tq,
                        const float* __restrict__ Wk, const float* __restrict__ Tk,
                        float* __restrict__ qn, float* __restrict__ kn)
{
  const int gw = (blockIdx.x * 256 + threadIdx.x) >> 6;
  const int lane = threadIdx.x & 63;
  const float* Wm = (gw < 512) ? Wq : Wk;
  const float* Tm = (gw < 512) ? Tq : Tk;
  const int c = gw & 511;
  float s = 0.f;
  for (int r = lane; r < 512; r += 64) s += Wm[(size_t)r * 512 + c] * Tm[(size_t)r * 512 + c];
  for (int off = 32; off > 0; off >>= 1) s += __shfl_down(s, off);
  if (lane == 0) {
    float n = sqrtf(fmaxf(s, 0.f));
    ((gw < 512) ? qn : kn)[c] = fmaxf(n, 1e-12f);
  }
}

// ---------------- per-head logits + softmax ----------------
__global__ __launch_bounds__(256) void k_attn(const float* __restrict__ Wk, const float* __restrict__ Tq,
    const float* __restrict__ qn, const float* __restrict__ kn,
    const float* __restrict__ rescale, float* __restrict__ attn)
{
  const int h = blockIdx.x, hd = h * 64;
  __shared__ float Ks[64][68];
  __shared__ float Qs[64][68];
  __shared__ float Ss[64][65];
  const int tx = threadIdx.x & 15, ty = threadIdx.x >> 4;
  float acc[4][4] = {};
  for (int k0 = 0; k0 < 512; k0 += 64) {
    __syncthreads();
#pragma unroll
    for (int p = 0; p < 4; p++) {
      int r = ty + p * 16;
      float4 a = *(const float4*)&Wk[(size_t)(k0 + r) * 512 + hd + tx * 4];
      float4 b = *(const float4*)&Tq[(size_t)(k0 + r) * 512 + hd + tx * 4];
      *(float4*)&Ks[r][tx * 4] = a;
      *(float4*)&Qs[r][tx * 4] = b;
    }
    __syncthreads();
    for (int kk = 0; kk < 64; kk++) {
      float a0 = Ks[kk][ty*4+0], a1 = Ks[kk][ty*4+1], a2 = Ks[kk][ty*4+2], a3 = Ks[kk][ty*4+3];
      float4 bq = *(const float4*)&Qs[kk][tx * 4];
      acc[0][0] += a0*bq.x; acc[0][1] += a0*bq.y; acc[0][2] += a0*bq.z; acc[0][3] += a0*bq.w;
      acc[1][0] += a1*bq.x; acc[1][1] += a1*bq.y; acc[1][2] += a1*bq.z; acc[1][3] += a1*bq.w;
      acc[2][0] += a2*bq.x; acc[2][1] += a2*bq.y; acc[2][2] += a2*bq.z; acc[2][3] += a2*bq.w;
      acc[3][0] += a3*bq.x; acc[3][1] += a3*bq.y; acc[3][2] += a3*bq.z; acc[3][3] += a3*bq.w;
    }
  }
#pragma unroll
  for (int u = 0; u < 4; u++)
#pragma unroll
    for (int v = 0; v < 4; v++)
      Ss[ty * 4 + u][tx * 4 + v] = acc[u][v];
  __syncthreads();
  if (threadIdx.x < 64) {
    const int i = threadIdx.x;
    const float sci = rescale[h] / kn[hd + i];
    float mx = -1e30f;
    for (int j = 0; j < 64; j++) {
      float L = Ss[i][j] * sci / qn[hd + j];
      Ss[i][j] = L;
      mx = fmaxf(mx, L);
    }
    float sum = 0.f;
    for (int j = 0; j < 64; j++) { float e = __expf(Ss[i][j] - mx); Ss[i][j] = e; sum += e; }
    float inv = 1.f / sum;
    for (int j = 0; j < 64; j++) attn[(size_t)h * 4096 + i * 64 + j] = Ss[i][j] * inv;
  }
}

// ---------------- fold attn into Wp ----------------
__global__ void k_w2t(const float* __restrict__ attn, const float* __restrict__ Wp, u16* __restrict__ W2T)
{
  const int h = blockIdx.x >> 3, e0 = (blockIdx.x & 7) * 64;
  __shared__ float As[64][65];
  for (int p = 0; p < 16; p++) {
    int idx = p * 256 + threadIdx.x;
    As[idx >> 6][idx & 63] = attn[(size_t)h * 4096 + idx];
  }
  __syncthreads();
  const int e = e0 + (threadIdx.x & 63);
  const int j4 = threadIdx.x >> 6;
  float s[16];
#pragma unroll
  for (int jj = 0; jj < 16; jj++) s[jj] = 0.f;
  for (int i = 0; i < 64; i++) {
    float wv_ = Wp[(size_t)(h * 64 + i) * 512 + e];
#pragma unroll
    for (int jj = 0; jj < 16; jj++) s[jj] += As[i][j4 * 16 + jj] * wv_;
  }
#pragma unroll
  for (int jj = 0; jj < 16; jj++)
    W2T[(size_t)e * 512 + h * 64 + j4 * 16 + jj] = f2bf(s[jj]);
}

// ---------------- SAR branch ----------------
__global__ void k_conv3(const float* __restrict__ sar, const float* __restrict__ w3,
                        const float* __restrict__ b3, float* __restrict__ a)
{
  const int oc = blockIdx.y;
  const int p = blockIdx.x * 256 + threadIdx.x;
  const int y = p >> 8, x = p & 255;
  float s = b3[oc];
#pragma unroll
  for (int ic = 0; ic < 2; ic++) {
    const float* img = sar + ic * 65536;
    const float* w = w3 + oc * 18 + ic * 9;
#pragma unroll
    for (int k = 0; k < 9; k++) {
      int yy = y + k / 3 - 1, xx = x + k % 3 - 1;
      if ((unsigned)yy < 256u && (unsigned)xx < 256u) s += w[k] * img[yy * 256 + xx];
    }
  }
  a[oc * 65536 + p] = s;
}

__global__ void k_bnstats(const float* __restrict__ a, const float* __restrict__ g,
                          const float* __restrict__ b, float* __restrict__ bnp)
{
  const int ch = blockIdx.x;
  const int tid = threadIdx.x;
  const float* src = a + ch * 65536;
  float s = 0.f, sq = 0.f;
  for (int i = tid; i < 65536; i += 256) { float v = src[i]; s += v; sq += v * v; }
  __shared__ float rs[256], rq[256];
  rs[tid] = s; rq[tid] = sq;
  __syncthreads();
  for (int o = 128; o > 0; o >>= 1) {
    if (tid < o) { rs[tid] += rs[tid + o]; rq[tid] += rq[tid + o]; }
    __syncthreads();
  }
  if (tid == 0) {
    float mu = rs[0] * (1.f / 65536.f);
    float var = rq[0] * (1.f / 65536.f) - mu * mu;
    float scale = g[ch] / sqrtf(var + 1e-5f);
    bnp[ch] = scale;
    bnp[2 + ch] = b[ch] - mu * scale;
  }
}

__global__ void k_sar2(const float* __restrict__ a, const float* __restrict__ bnp,
                       const float* __restrict__ sb, float* __restrict__ ss)
{
  const int p = blockIdx.x * 256 + threadIdx.x;
  const int y = p >> 8, x = p & 255;
  const float sc0 = bnp[0], sc1 = bnp[1], sh0 = bnp[2], sh1 = bnp[3];
  float bs[9];
  float bn0c = 0.f, bn1c = 0.f;
#pragma unroll
  for (int k = 0; k < 9; k++) {
    int yy = y + k / 3 - 1, xx = x + k % 3 - 1;
    float v0 = 0.f, v1 = 0.f;
    if ((unsigned)yy < 256u && (unsigned)xx < 256u) {
      int q = yy * 256 + xx;
      v0 = a[q] * sc0 + sh0;
      v1 = a[65536 + q] * sc1 + sh1;
    }
    bs[k] = v0 + v1;
    if (k == 4) { bn0c = v0; bn1c = v1; }
  }
  float gv = (bs[6] + 2.f * bs[7] + bs[8]) - (bs[0] + 2.f * bs[1] + bs[2]);
  float gh = (bs[2] + 2.f * bs[5] + bs[8]) - (bs[0] + 2.f * bs[3] + bs[6]);
  float s0 = gv + sb[0], s1 = gh + sb[1], s2 = gv + sb[2], s3 = gh + sb[3];
  ss[p]         = sqrtf(s0 * s0 + s1 * s1) + bn0c;
  ss[65536 + p] = sqrtf(s2 * s2 + s3 * s3) + bn1c;
}

// =====================================================================
// Mask via MFMA GEMM. mask = L1 + beta_c*(W(p)-wsum_c) + sigmoid(L2),
// L1/L2 linear in the 50-value patch; K=192 hi/lo-compensated bf16 GEMM.
// 2-phase double-buffered staging; epilogue stages mask (f32) through LDS
// so the VB gate is coalesced ushort8 RMW.
// =====================================================================

// ---- k_dwprep: build BM [1024][192] bf16 and border tables TB [512][32] ----
__global__ void k_dwprep(const float* __restrict__ dw, const float* __restrict__ db,
                         const float* __restrict__ w2, const float* __restrict__ b2,
                         const float* __restrict__ w32, const float* __restrict__ b32,
                         u16* __restrict__ BM, float* __restrict__ TB)
{
  const int c = blockIdx.x * 256 + threadIdx.x;
  if (c >= 512) return;
  float d[25];
  float wsum = 0.f;
#pragma unroll
  for (int t = 0; t < 25; t++) { d[t] = dw[c * 25 + t]; wsum += d[t]; }
  const float a = w2[2 * c], b = w2[2 * c + 1], beta = b2[c];
  const float C1 = beta * (1.f + wsum) + db[c];

  u16* rL1 = BM + (size_t)((c >> 6) * 128 + (c & 63)) * 192;
  u16* rL2 = rL1 + (size_t)64 * 192;

#pragma unroll
  for (int k = 0; k < 64; k++) {
    float v1;
    if (k < 25)       v1 = a * (d[k] + (k == 12 ? 1.f : 0.f));
    else if (k < 50)  v1 = b * (d[k - 25] + (k == 37 ? 1.f : 0.f));
    else if (k == 63) v1 = C1;
    else              v1 = 0.f;
    u16 h = f2bf(v1); u16 l = f2bf(v1 - bf2f(h));
    rL1[k] = h; rL1[64 + k] = h; rL1[128 + k] = l;
  }
#pragma unroll
  for (int k = 0; k < 64; k++) {
    float v2 = 0.f;
    if (k < 50) {
      const int t = (k < 25) ? k : (k - 25);
      const int dy = t / 5 - 2, dx = t % 5 - 2;
      if (dy >= -1 && dy <= 1 && dx >= -1 && dx <= 1)
        v2 = w32[c * 18 + ((k < 25) ? 0 : 9) + (dy + 1) * 3 + (dx + 1)];
    }
    if (k == 63) v2 = b32[c];
    u16 h = f2bf(v2); u16 l = f2bf(v2 - bf2f(h));
    rL2[k] = h; rL2[64 + k] = h; rL2[128 + k] = l;
  }

  // border tables: W = wsum - T[mt] - B[mb] - L[ml] - R[mr] + corners
  float rs[5], cs[5];
#pragma unroll
  for (int i = 0; i < 5; i++) {
    rs[i] = d[i*5] + d[i*5+1] + d[i*5+2] + d[i*5+3] + d[i*5+4];
    cs[i] = d[i] + d[5+i] + d[10+i] + d[15+i] + d[20+i];
  }
  float* tb = TB + (size_t)c * 32;
  tb[0] = rs[0];  tb[1] = rs[0] + rs[1];          // T1, T2 (missing top rows)
  tb[2] = rs[4];  tb[3] = rs[3] + rs[4];          // B1, B2
  tb[4] = cs[0];  tb[5] = cs[0] + cs[1];          // L1, L2
  tb[6] = cs[4];  tb[7] = cs[3] + cs[4];          // R1, R2
  tb[8]  = d[0];           tb[9]  = d[0] + d[1];            // TL(1,1) TL(1,2)
  tb[10] = d[0] + d[5];    tb[11] = d[0] + d[1] + d[5] + d[6];
  tb[12] = d[4];           tb[13] = d[3] + d[4];            // TR
  tb[14] = d[4] + d[9];    tb[15] = d[3] + d[4] + d[8] + d[9];
  tb[16] = d[20];          tb[17] = d[20] + d[21];          // BL
  tb[18] = d[15] + d[20];  tb[19] = d[15] + d[16] + d[20] + d[21];
  tb[20] = d[24];          tb[21] = d[23] + d[24];          // BR
  tb[22] = d[19] + d[24];  tb[23] = d[18] + d[19] + d[23] + d[24];
#pragma unroll
  for (int i = 24; i < 32; i++) tb[i] = 0.f;
}

// ---- k_patch: build P [65536][192] bf16 patch matrix from SS ----
__global__ __launch_bounds__(256) void k_patch(const float* __restrict__ ss, u16* __restrict__ P)
{
  __shared__ float s0r[5][264];
  __shared__ float s1r[5][264];
  const int y = blockIdx.x;       // one image row per block
  const int tid = threadIdx.x;
  for (int i = tid; i < 1300; i += 256) {
    const int r = i / 260, col = i - r * 260;
    const int yy = y + r - 2, xx = col - 2;
    const bool in = ((unsigned)yy < 256u) & ((unsigned)xx < 256u);
    const int gp = yy * 256 + xx;
    s0r[r][col] = in ? ss[gp] : 0.f;
    s1r[r][col] = in ? ss[65536 + gp] : 0.f;
  }
  __syncthreads();
  const int x = tid;
  unsigned arr32[64];              // k[0..127]; k[128..191] is a copy of k[0..63]
#pragma unroll
  for (int i = 0; i < 64; i++) arr32[i] = 0u;
#define PUTK(k, v) arr32[(k) >> 1] |= ((unsigned)(v)) << (((k) & 1) * 16)
#pragma unroll
  for (int dy = 0; dy < 5; dy++)
#pragma unroll
    for (int dx = 0; dx < 5; dx++) {
      const int t = dy * 5 + dx;
      const float v0 = s0r[dy][x + dx];
      const float v1 = s1r[dy][x + dx];
      const u16 h0 = f2bf(v0); const u16 l0 = f2bf(v0 - bf2f(h0));
      const u16 h1 = f2bf(v1); const u16 l1 = f2bf(v1 - bf2f(h1));
      PUTK(t, h0);      PUTK(25 + t, h1);
      PUTK(64 + t, l0); PUTK(89 + t, l1);
    }
  PUTK(63, 0x3F80u);               // 1.0 for bias slot (block2 copy gives k191=1.0)
#undef PUTK
  unsigned* dst = (unsigned*)(P + (size_t)(y * 256 + x) * 192);
#pragma unroll
  for (int i = 0; i < 16; i++)
    *(uint4*)(dst + i * 4) = *(const uint4*)(arr32 + i * 4);
#pragma unroll
  for (int i = 0; i < 8; i++)
    *(uint4*)(dst + 64 + i * 4) = *(const uint4*)(arr32 + i * 4);
}

// ---- k_maskmm: C = P @ BM^T fused with sigmoid/border/V-gate, in-place VB ----
// Tile: M=128 px, N=128 (64 ch: n<64 -> L1, n>=64 -> L2), K=192, 2-phase dbuf.
// 4 waves stacked in M (wave tile 32x128) so each lane holds L1 and L2 of the
// SAME channel. Mask staged f32 in LDS; VB gated with coalesced ushort8 RMW.
__global__ __launch_bounds__(256) void k_maskmm(
    const u16* __restrict__ P, const u16* __restrict__ BM,
    const float* __restrict__ TB, const float* __restrict__ beta_p,
    u16* __restrict__ VB)
{
  // pool: 2 staging buffers (32 KiB) aliased over mask tile [128][68] f32 (34 KiB)
  __shared__ __align__(16) float lds_pool[128 * 68];
  uint4* smem = (uint4*)lds_pool;
  const int tid  = threadIdx.x;
  const int lane = tid & 63;
  const int wv   = tid >> 6;
  const int m0   = blockIdx.x * 128;
  const int g    = blockIdx.y;          // channel group (64 ch)

  const int q0 = tid, q1 = tid + 256;
  const size_t arow0 = (size_t)(m0 + (q0 >> 2)) * 192 + (q0 & 3) * 8;
  const size_t arow1 = (size_t)(m0 + (q1 >> 2)) * 192 + (q1 & 3) * 8;
  const size_t brow0 = (size_t)(g * 128 + (q0 >> 2)) * 192 + (q0 & 3) * 8;
  const size_t brow1 = (size_t)(g * 128 + (q1 >> 2)) * 192 + (q1 & 3) * 8;

  f32x4 acc[2][8] = {};
  const int ko = (lane >> 4) * 16;
  const int ma = lane & 15;

  // prologue: stage k0=0 into buf 0
  GLOAD_LDS16(&P[arow0],  &smem[q0]);
  GLOAD_LDS16(&P[arow1],  &smem[q1]);
  GLOAD_LDS16(&BM[brow0], &smem[512 + q0]);
  GLOAD_LDS16(&BM[brow1], &smem[512 + q1]);
  __syncthreads();

  int cur = 0;
  for (int t = 0; t < 6; ++t) {
    if (t < 5) {
      const int kn = (t + 1) * 32;
      uint4* nb = &smem[(cur ^ 1) * 1024];
      GLOAD_LDS16(&P[arow0 + kn],  &nb[q0]);
      GLOAD_LDS16(&P[arow1 + kn],  &nb[q1]);
      GLOAD_LDS16(&BM[brow0 + kn], &nb[512 + q0]);
      GLOAD_LDS16(&BM[brow1 + kn], &nb[512 + q1]);
    }
    const char* lAc = (const char*)&smem[cur * 1024];
    const char* lBc = (const char*)&smem[cur * 1024 + 512];
    short8 af[2], bfr[8];
#pragma unroll
    for (int mt = 0; mt < 2; mt++)
      af[mt] = *(const short8*)(lAc + (wv * 32 + mt * 16 + ma) * 64 + ko);
#pragma unroll
    for (int nt = 0; nt < 8; nt++)
      bfr[nt] = *(const short8*)(lBc + (nt * 16 + ma) * 64 + ko);
#pragma unroll
    for (int mt = 0; mt < 2; mt++)
#pragma unroll
      for (int nt = 0; nt < 8; nt++)
        acc[mt][nt] = __builtin_amdgcn_mfma_f32_16x16x32_bf16(af[mt], bfr[nt], acc[mt][nt], 0, 0, 0);
    __syncthreads();
    cur ^= 1;
  }

  // pool reused as mask tile (last barrier above guarantees staging reads done)
  const int col = lane & 15, rq = (lane >> 4) * 4;
  const int y   = m0 >> 8;                       // block covers half a row: y uniform
  const int mty = (y < 2) ? (2 - y) : 0;
  const int mby = (y > 253) ? (y - 253) : 0;
#pragma unroll
  for (int mt = 0; mt < 2; mt++) {
#pragma unroll
    for (int nt = 0; nt < 4; nt++) {
      const int ch = g * 64 + nt * 16 + col;
#pragma unroll
      for (int r = 0; r < 4; r++) {
        const int pxl = wv * 32 + mt * 16 + rq + r;      // 0..127
        const float L1 = acc[mt][nt][r];
        const float L2 = acc[mt][nt + 4][r];
        const int x  = (m0 + pxl) & 255;
        const int ml = (x < 2) ? (2 - x) : 0;
        const int mr = (x > 253) ? (x - 253) : 0;
        float wc = 0.f;
        if (mty | mby | ml | mr) {
          const float* tb = &TB[(size_t)ch * 32];
          float W = 0.f;
          if (mty) W -= tb[mty - 1];
          if (mby) W -= tb[2 + mby - 1];
          if (ml)  W -= tb[4 + ml - 1];
          if (mr)  W -= tb[6 + mr - 1];
          if (mty && ml) W += tb[8  + (mty - 1) * 2 + (ml - 1)];
          if (mty && mr) W += tb[12 + (mty - 1) * 2 + (mr - 1)];
          if (mby && ml) W += tb[16 + (mby - 1) * 2 + (ml - 1)];
          if (mby && mr) W += tb[20 + (mby - 1) * 2 + (mr - 1)];
          wc = beta_p[ch] * W;
        }
        const float sig = 1.f / (1.f + __expf(-L2));
        lds_pool[pxl * 68 + nt * 16 + col] = L1 + wc + sig;
      }
    }
  }
  __syncthreads();
  // coalesced gate: 4 chunks/thread, chunk = 8 ch (16 B) of one pixel row
#pragma unroll
  for (int k = 0; k < 4; k++) {
    const int cid = k * 256 + tid;
    const int pxl = cid >> 3;              // 0..127
    const int cp  = (cid & 7) * 8;         // 0..56
    const float4 ma0 = *(const float4*)&lds_pool[pxl * 68 + cp];
    const float4 ma1 = *(const float4*)&lds_pool[pxl * 68 + cp + 4];
    u16* vp = &VB[(size_t)(m0 + pxl) * 512 + g * 64 + cp];
    short8 vv = *(const short8*)vp;
    short8 o;
    o[0] = (short)f2bf(bf2f((u16)vv[0]) * ma0.x);
    o[1] = (short)f2bf(bf2f((u16)vv[1]) * ma0.y);
    o[2] = (short)f2bf(bf2f((u16)vv[2]) * ma0.z);
    o[3] = (short)f2bf(bf2f((u16)vv[3]) * ma0.w);
    o[4] = (short)f2bf(bf2f((u16)vv[4]) * ma1.x);
    o[5] = (short)f2bf(bf2f((u16)vv[5]) * ma1.y);
    o[6] = (short)f2bf(bf2f((u16)vv[6]) * ma1.z);
    o[7] = (short)f2bf(bf2f((u16)vv[7]) * ma1.w);
    *(short8*)vp = o;
  }
}

// =====================================================================
// Vectorized depthwise 3x3 (plane layout). Wave = 16 x-subgroups x 4 channels;
// lane loads ushort4 per row, halo via shfl; edge subgroups do predicated u16 load.
// =====================================================================
DEVFN void dw3x3_row4(const u16* plane, int y, int x0, int sub,
                      const float* w9, float& s0, float& s1, float& s2, float& s3)
{
#pragma unroll
  for (int r = 0; r < 3; r++) {
    int yy = y + r - 1;
    if ((unsigned)yy < 256u) {       // block-uniform branch
      const int base = yy * 256 + x0 + sub * 4;
      ushort4 p = *(const ushort4*)&plane[base];
      float v0 = bf2f(p.x), v1 = bf2f(p.y), v2 = bf2f(p.z), v3 = bf2f(p.w);
      float lf = __shfl_up(v3, 1);
      float rt = __shfl_down(v0, 1);
      if (sub == 0)  lf = (x0 > 0)   ? bf2f(plane[yy * 256 + x0 - 1])  : 0.f;
      if (sub == 15) rt = (x0 < 192) ? bf2f(plane[yy * 256 + x0 + 64]) : 0.f;
      const float wa = w9[r * 3], wb = w9[r * 3 + 1], wc = w9[r * 3 + 2];
      s0 += wa * lf + wb * v0 + wc * v1;
      s1 += wa * v0 + wb * v1 + wc * v2;
      s2 += wa * v1 + wb * v2 + wc * v3;
      s3 += wa * v2 + wb * v3 + wc * rt;
    }
  }
}

// pe1: dconv3x3(VT) -> exact GELU -> GT (plane layout, vectorized)
__global__ __launch_bounds__(256) void k_pe1v(const u16* __restrict__ vt,
    const float* __restrict__ w, u16* __restrict__ gt)
{
  const int t = blockIdx.x;
  const int y = t >> 2, x0 = (t & 3) * 64;
  const int cg = blockIdx.y * 64;
  const int lane = threadIdx.x & 63, wvq = threadIdx.x >> 6;
  const int sub = lane & 15, chq = lane >> 4;
#pragma unroll
  for (int i = 0; i < 4; i++) {
    const int c = cg + wvq * 16 + i * 4 + chq;
    const u16* plane = vt + (size_t)c * 65536;
    float w9[9];
#pragma unroll
    for (int k = 0; k < 9; k++) w9[k] = w[c * 9 + k];
    float s0 = 0.f, s1 = 0.f, s2 = 0.f, s3 = 0.f;
    dw3x3_row4(plane, y, x0, sub, w9, s0, s1, s2, s3);
    const float ksc = 0.70710678118654752f;
    s0 = 0.5f * s0 * (1.f + erff(s0 * ksc));
    s1 = 0.5f * s1 * (1.f + erff(s1 * ksc));
    s2 = 0.5f * s2 * (1.f + erff(s2 * ksc));
    s3 = 0.5f * s3 * (1.f + erff(s3 * ksc));
    ushort4 o; o.x = f2bf(s0); o.y = f2bf(s1); o.z = f2bf(s2); o.w = f2bf(s3);
    *(ushort4*)&gt[(size_t)c * 65536 + y * 256 + x0 + sub * 4] = o;
  }
}

// pe2: dconv3x3(GT), LDS transpose, coalesced bf16 write to PEB [n][c].
// (PE is added to out inside the final GEMM epilogue — no fp32 RMW.)
__global__ __launch_bounds__(256) void k_pe2v(const u16* __restrict__ gt,
    const float* __restrict__ w, u16* __restrict__ peb)
{
  __shared__ float tile[64][65];
  const int t = blockIdx.x;
  const int y = t >> 2, x0 = (t & 3) * 64;
  const int cg = blockIdx.y * 64;
  const int lane = threadIdx.x & 63, wvq = threadIdx.x >> 6;
  const int sub = lane & 15, chq = lane >> 4;
#pragma unroll
  for (int i = 0; i < 4; i++) {
    const int cl = wvq * 16 + i * 4 + chq;
    const int c = cg + cl;
    const u16* plane = gt + (size_t)c * 65536;
    float w9[9];
#pragma unroll
    for (int k = 0; k < 9; k++) w9[k] = w[c * 9 + k];
    float s0 = 0.f, s1 = 0.f, s2 = 0.f, s3 = 0.f;
    dw3x3_row4(plane, y, x0, sub, w9, s0, s1, s2, s3);
    tile[cl][sub * 4 + 0] = s0;
    tile[cl][sub * 4 + 1] = s1;
    tile[cl][sub * 4 + 2] = s2;
    tile[cl][sub * 4 + 3] = s3;
  }
  __syncthreads();
  // 64 px x 64 ch = 512 ushort8 chunks; 2 per thread, fully coalesced 16B/lane
#pragma unroll
  for (int k = 0; k < 2; k++) {
    const int cid = k * 256 + threadIdx.x;
    const int q = cid & 7, pl = cid >> 3;          // q: 8-ch group, pl: pixel 0..63
    short8 o;
#pragma unroll
    for (int j = 0; j < 8; j++) o[j] = (short)f2bf(tile[q * 8 + j][pl]);
    *(short8*)&peb[(size_t)(y * 256 + x0 + pl) * 512 + cg + q * 8] = o;
  }
}

// =====================================================================
extern "C" void kernel_launch(void* const* d_in, const int* in_sizes, int n_in,
                              void* d_out, int out_size, void* d_ws, size_t ws_size,
                              hipStream_t stream)
{
  (void)in_sizes; (void)n_in; (void)out_size;
  const float* x    = (const float*)d_in[0];
  const float* sar  = (const float*)d_in[1];
  const float* Wq   = (const float*)d_in[2];
  const float* Wk   = (const float*)d_in[3];
  const float* Wv   = (const float*)d_in[4];
  const float* resc = (const float*)d_in[5];
  const float* Wp   = (const float*)d_in[6];
  const float* bp   = (const float*)d_in[7];
  const float* pe1w = (const float*)d_in[8];
  const float* pe2w = (const float*)d_in[9];
  const float* w3   = (const float*)d_in[10];
  const float* b3   = (const float*)d_in[11];
  const float* bng  = (const float*)d_in[12];
  const float* bnb  = (const float*)d_in[13];
  const float* sb   = (const float*)d_in[14];
  const float* w2c  = (const float*)d_in[15];
  const float* b2c  = (const float*)d_in[16];
  const float* w32  = (const float*)d_in[17];
  const float* b32  = (const float*)d_in[18];
  const float* dw   = (const float*)d_in[19];
  const float* db   = (const float*)d_in[20];
  float* out = (float*)d_out;

  if (ws_size < WS_NEEDED)
    fprintf(stderr, "MS_MSA: workspace too small: have %zu need %zu\n", ws_size, WS_NEEDED);

  char* ws = (char*)d_ws;
  u16* XB    = (u16*)(ws + OFF_XB);
  u16* XBT   = (u16*)(ws + OFF_XBT);
  u16* VB    = (u16*)(ws + OFF_VB);
  u16* VT    = (u16*)(ws + OFF_VT);
  float* GPART = (float*)(ws + OFF_GPART);
  float* G     = (float*)(ws + OFF_G);
  float* TQ    = (float*)(ws + OFF_TQ);
  float* TK    = (float*)(ws + OFF_TK);
  u16* WVT   = (u16*)(ws + OFF_WVT);
  u16* W2T   = (u16*)(ws + OFF_W2T);
  float* ASAR = (float*)(ws + OFF_ASAR);
  float* SS   = (float*)(ws + OFF_SS);
  float* BNP  = (float*)(ws + OFF_BNP);
  float* QN   = (float*)(ws + OFF_QN);
  float* KN   = (float*)(ws + OFF_KN);
  float* ATTN = (float*)(ws + OFF_ATTN);
  u16*  BM   = (u16*)(ws + OFF_BM);
  float* TBt  = (float*)(ws + OFF_TB);
  u16* GT  = XBT;                 // alias: XBT dead after Gram
  u16* P   = (u16*)(ws + OFF_GPART);  // alias: GPART dead after k_reduce_g
  u16* PEB = XB;                  // alias: XB dead after gemm_bt<0>

  // --- x -> bf16 (row + transposed) ---
  k_cast_transpose<<<dim3(1024, 8), 256, 0, stream>>>(x, XB, XBT);
  // --- G = X^T X ---
  gemm_bt<1><<<dim3(4, 4, GSPLIT), 256, 0, stream>>>(XBT, NTOK, XBT, NTOK, GKLEN, GPART, nullptr, nullptr);
  k_reduce_g<<<1024, 256, 0, stream>>>(GPART, G);
  // --- v_inp = x @ Wv ---
  k_transpose_w<<<dim3(8, 8), 256, 0, stream>>>(Wv, WVT);
  gemm_bt<0><<<dim3(512, 4), 256, 0, stream>>>(XB, 512, WVT, 512, 512, VB, nullptr, nullptr);
  k_tbf16<<<dim3(1024, 8), 256, 0, stream>>>(VB, VT, 65536, 512);   // VT = ungated v^T for pe1
  // --- attention stats ---
  k_gw<<<dim3(8, 8, 2), 256, 0, stream>>>(G, Wq, Wk, TQ, TK);
  k_norms<<<256, 256, 0, stream>>>(Wq, TQ, Wk, TK, QN, KN);
  k_attn<<<8, 256, 0, stream>>>(Wk, TQ, QN, KN, resc, ATTN);
  k_w2t<<<64, 256, 0, stream>>>(ATTN, Wp, W2T);
  // --- SAR branch ---
  k_conv3<<<dim3(256, 2), 256, 0, stream>>>(sar, w3, b3, ASAR);
  k_bnstats<<<2, 256, 0, stream>>>(ASAR, bng, bnb, BNP);
  k_sar2<<<256, 256, 0, stream>>>(ASAR, BNP, sb, SS);
  // --- mask via compensated bf16 MFMA GEMM, gate V in-place ([n][c]) ---
  k_dwprep<<<2, 256, 0, stream>>>(dw, db, w2c, b2c, w32, b32, BM, TBt);
  k_patch<<<256, 256, 0, stream>>>(SS, P);
  k_maskmm<<<dim3(512, 8), 256, 0, stream>>>(P, BM, TBt, b2c, VB);
  // --- positional branch -> PEB bf16 [n][c] (XB alias) ---
  k_pe1v<<<dim3(1024, 8), 256, 0, stream>>>(VT, pe1w, GT);
  k_pe2v<<<dim3(1024, 8), 256, 0, stream>>>(GT, pe2w, PEB);
  // --- out = (v*mask) @ W2 + bp + PE  (single writer of out) ---
  gemm_bt<3><<<dim3(512, 4), 256, 0, stream>>>(VB, 512, W2T, 512, 512, out, bp, PEB);
}